// Round 9
// baseline (317.772 us; speedup 1.0000x reference)
//
#include <hip/hip_runtime.h>
#include <stdint.h>

#define LOG2E 1.4426950408889634f

typedef __attribute__((ext_vector_type(8))) short short8;
typedef __attribute__((ext_vector_type(4))) float floatx4;
typedef unsigned int u32;

__device__ __forceinline__ float bf2f(unsigned short h) {
  union { unsigned int u; float f; } v; v.u = ((unsigned int)h) << 16; return v.f;
}
__device__ __forceinline__ unsigned short f2bf(float f) {
  union { float f; unsigned int u; } v; v.f = f;
  unsigned int r = v.u + 0x7FFFu + ((v.u >> 16) & 1u);
  return (unsigned short)(r >> 16);
}
__device__ __forceinline__ u32 fbits(float f) {
  union { float f; u32 u; } v; v.f = f; return v.u;
}
// async global->LDS, 16B per lane. dst must be wave-contiguous (base + lane*16).
__device__ __forceinline__ void async16(void* lds, const void* g) {
  __builtin_amdgcn_global_load_lds((const __attribute__((address_space(1))) u32*)g,
                                   (__attribute__((address_space(3))) u32*)lds, 16, 0, 0);
}

// ---------------------------------------------------------------------------
// prep1: fp32->bf16 x-convert AND all 4 weight transposes in ONE launch.
__global__ __launch_bounds__(256) void prep1(const float* __restrict__ x,
                                             const float* __restrict__ Wq,
                                             const float* __restrict__ Wk,
                                             const float* __restrict__ Wv,
                                             const float* __restrict__ Wo,
                                             unsigned short* __restrict__ xbf,
                                             unsigned short* __restrict__ WTqkv,
                                             unsigned short* __restrict__ WoT) {
  __shared__ unsigned short tile[64][65];
  int bid = blockIdx.x;
  if (bid < 4096) {
    int i = (bid * 256 + threadIdx.x) * 8;
    float4 a = ((const float4*)(x + i))[0];
    float4 b = ((const float4*)(x + i))[1];
    union { uint4 v; unsigned short u[8]; } o;
    o.u[0] = f2bf(a.x); o.u[1] = f2bf(a.y); o.u[2] = f2bf(a.z); o.u[3] = f2bf(a.w);
    o.u[4] = f2bf(b.x); o.u[5] = f2bf(b.y); o.u[6] = f2bf(b.z); o.u[7] = f2bf(b.w);
    *(uint4*)(xbf + i) = o.v;
    return;
  }
  bid -= 4096;
  const int R = 2048;
  const float* src; unsigned short* dst; int C;
  if (bid < 1024) { src = Wq; dst = WTqkv; C = 2048; }
  else if (bid < 1280) { src = Wk; dst = WTqkv + (size_t)2048 * 2048; C = 512; bid -= 1024; }
  else if (bid < 1536) { src = Wv; dst = WTqkv + (size_t)2048 * 2048 + (size_t)512 * 2048; C = 512; bid -= 1280; }
  else { src = Wo; dst = WoT; C = 2048; bid -= 1536; }

  int tc = C >> 6;
  int br = bid / tc, bc = bid % tc;
  int r0 = br << 6, c0 = bc << 6;
  int i = threadIdx.x >> 2, cc = (threadIdx.x & 3) << 4;
  const float4* g = (const float4*)(src + (size_t)(r0 + i) * C + c0 + cc);
  float4 f0 = g[0], f1 = g[1], f2 = g[2], f3 = g[3];
  unsigned short u[16];
  u[0]=f2bf(f0.x); u[1]=f2bf(f0.y); u[2]=f2bf(f0.z); u[3]=f2bf(f0.w);
  u[4]=f2bf(f1.x); u[5]=f2bf(f1.y); u[6]=f2bf(f1.z); u[7]=f2bf(f1.w);
  u[8]=f2bf(f2.x); u[9]=f2bf(f2.y); u[10]=f2bf(f2.z); u[11]=f2bf(f2.w);
  u[12]=f2bf(f3.x); u[13]=f2bf(f3.y); u[14]=f2bf(f3.z); u[15]=f2bf(f3.w);
#pragma unroll
  for (int j = 0; j < 16; ++j) tile[i][cc + j] = u[j];
  __syncthreads();
  union { uint4 v[2]; unsigned short u[16]; } buf;
#pragma unroll
  for (int j = 0; j < 16; ++j) buf.u[j] = tile[cc + j][i];
  uint4* o = (uint4*)(dst + (size_t)(c0 + i) * R + r0 + cc);
  o[0] = buf.v[0]; o[1] = buf.v[1];
}

// ---------------------------------------------------------------------------
// 8-phase 256x192 NT GEMM, bf16 out — qkv projection. R6: 256 blocks = 1/CU.
__global__ __launch_bounds__(512, 2) void gemm_nt_256x192(const unsigned short* __restrict__ A,
                                                          const unsigned short* __restrict__ BT,
                                                          unsigned short* __restrict__ C,
                                                          int M, int N, int K) {
  (void)M;
  __shared__ unsigned short As[2][256 * 64];
  __shared__ unsigned short Bs[2][192 * 64];
  const int nbn = N / 192;
  const int nwg = gridDim.x;
  int wg = blockIdx.x;
  {  // XCD-aware swizzle (bijective: nwg % 8 == 0)
    int cpx = nwg >> 3;
    wg = (wg & 7) * cpx + (wg >> 3);
  }
  const int m0 = (wg / nbn) << 8;
  const int n0 = (wg % nbn) * 192;
  const int tid = threadIdx.x;
  const int lane = tid & 63, wave = tid >> 6;
  const int l15 = lane & 15, quad = lane >> 4;
  const int wr = wave >> 2, wc = wave & 3;   // 2 x 4 wave grid
  const int rA = wr * 128 + l15;             // + mf*16, mf in [0,8)
  const int rB = wc * 48 + l15;              // + nf*16, nf in [0,3)

  floatx4 acc[8][3];
#pragma unroll
  for (int i = 0; i < 8; ++i)
#pragma unroll
    for (int j = 0; j < 3; ++j) acc[i][j] = (floatx4){0.f, 0.f, 0.f, 0.f};

  const unsigned short* Ag = A + (size_t)m0 * K;
  const unsigned short* Bg = BT + (size_t)n0 * K;

  // A row-half h (128 rows x 64k = 16KB): 2 loads/thread.
  auto STAGE_A = [&](unsigned short* dst, const unsigned short* g, int h) {
#pragma unroll
    for (int j = 0; j < 2; ++j) {
      int idx = j * 512 + tid;              // [0,1024)
      int row = h * 128 + (idx >> 3);
      int cl = (idx & 7) ^ (row & 7);
      async16(dst + (size_t)h * 8192 + (size_t)idx * 8, g + (size_t)row * K + cl * 8);
    }
  };
  // B full tile (192 rows x 64k = 24KB): 3 loads/thread.
  auto STAGE_B = [&](unsigned short* dst, const unsigned short* g) {
#pragma unroll
    for (int j = 0; j < 3; ++j) {
      int idx = j * 512 + tid;              // [0,1536)
      int row = idx >> 3;
      int cl = (idx & 7) ^ (row & 7);
      async16(dst + (size_t)idx * 8, g + (size_t)row * K + cl * 8);
    }
  };
  auto RD = [&](const unsigned short* buf, int row, int ks) -> short8 {
    int sc = ((ks << 2) + quad) ^ (row & 7);
    return *(const short8*)(buf + row * 64 + sc * 8);
  };

#define BAR() __builtin_amdgcn_s_barrier()
#define WAITL0() asm volatile("s_waitcnt lgkmcnt(0)" ::: "memory")

  // prologue: A(0) h0,h1 [4]; B(0) [3]; A(1) h0,h1 [4] = 11 loads/thread
  STAGE_A(As[0], Ag, 0); STAGE_A(As[0], Ag, 1);
  STAGE_B(Bs[0], Bg);
  STAGE_A(As[1], Ag + 64, 0); STAGE_A(As[1], Ag + 64, 1);
  asm volatile("s_waitcnt vmcnt(4)" ::: "memory");   // tile0 landed; A(1) in flight
  BAR();

  const int NT = K >> 6;
  short8 a0[4][2], a1[4][2], b0[2][2], b1[2];
  for (int t = 0; t < NT; ++t) {
    const unsigned short* Ac = As[t & 1];
    const unsigned short* Bc = Bs[t & 1];
    unsigned short* Ast = As[t & 1];         // stage target: A(t+2), in-place
    unsigned short* Bst = Bs[(t + 1) & 1];   // stage target: B(t+1)

    // ---- phase 1: read a0 (mf0-3) + b0 (nf0-1) [12]; stage B(t+1) full [3]
#pragma unroll
    for (int mf = 0; mf < 4; ++mf)
#pragma unroll
      for (int ks = 0; ks < 2; ++ks) a0[mf][ks] = RD(Ac, rA + mf * 16, ks);
#pragma unroll
    for (int nf = 0; nf < 2; ++nf)
#pragma unroll
      for (int ks = 0; ks < 2; ++ks) b0[nf][ks] = RD(Bc, rB + nf * 16, ks);
    if (t + 1 < NT) STAGE_B(Bst, Bg + (size_t)(t + 1) * 64);
    asm volatile("s_waitcnt lgkmcnt(8)" ::: "memory");
    BAR(); WAITL0();
    __builtin_amdgcn_s_setprio(1);
#pragma unroll
    for (int mf = 0; mf < 4; ++mf)
#pragma unroll
      for (int nf = 0; nf < 2; ++nf)
#pragma unroll
        for (int ks = 0; ks < 2; ++ks)
          acc[mf][nf] = __builtin_amdgcn_mfma_f32_16x16x32_bf16(a0[mf][ks], b0[nf][ks], acc[mf][nf], 0, 0, 0);
    __builtin_amdgcn_s_setprio(0);
    BAR();

    // ---- phase 2: read a1 (mf4-7) [8]
#pragma unroll
    for (int mf = 0; mf < 4; ++mf)
#pragma unroll
      for (int ks = 0; ks < 2; ++ks) a1[mf][ks] = RD(Ac, rA + 64 + mf * 16, ks);
    BAR(); WAITL0();
    __builtin_amdgcn_s_setprio(1);
#pragma unroll
    for (int mf = 0; mf < 4; ++mf)
#pragma unroll
      for (int nf = 0; nf < 2; ++nf)
#pragma unroll
        for (int ks = 0; ks < 2; ++ks)
          acc[4 + mf][nf] = __builtin_amdgcn_mfma_f32_16x16x32_bf16(a1[mf][ks], b0[nf][ks], acc[4 + mf][nf], 0, 0, 0);
    __builtin_amdgcn_s_setprio(0);
    BAR();

    // ---- phase 3: read b1 (nf2) [2]; stage A(t+2)h0 (A(t) dead after ph2)
#pragma unroll
    for (int ks = 0; ks < 2; ++ks) b1[ks] = RD(Bc, rB + 32, ks);
    if (t + 2 < NT) STAGE_A(Ast, Ag + (size_t)(t + 2) * 64, 0);
    BAR(); WAITL0();
    __builtin_amdgcn_s_setprio(1);
#pragma unroll
    for (int mf = 0; mf < 4; ++mf)
#pragma unroll
      for (int ks = 0; ks < 2; ++ks)
        acc[4 + mf][2] = __builtin_amdgcn_mfma_f32_16x16x32_bf16(a1[mf][ks], b1[ks], acc[4 + mf][2], 0, 0, 0);
    __builtin_amdgcn_s_setprio(0);
    BAR();

    // ---- phase 4: stage A(t+2)h1; counted vmcnt(4) per tile
    if (t + 2 < NT) {
      STAGE_A(Ast, Ag + (size_t)(t + 2) * 64, 1);
      asm volatile("s_waitcnt vmcnt(4)" ::: "memory");  // tile t+1 fully landed
    } else {
      asm volatile("s_waitcnt vmcnt(0)" ::: "memory");  // tail drain
    }
    BAR();
    __builtin_amdgcn_s_setprio(1);
#pragma unroll
    for (int mf = 0; mf < 4; ++mf)
#pragma unroll
      for (int ks = 0; ks < 2; ++ks)
        acc[mf][2] = __builtin_amdgcn_mfma_f32_16x16x32_bf16(a0[mf][ks], b1[ks], acc[mf][2], 0, 0, 0);
    __builtin_amdgcn_s_setprio(0);
    BAR();
  }
#undef BAR
#undef WAITL0

#pragma unroll
  for (int mf = 0; mf < 8; ++mf)
#pragma unroll
    for (int nf = 0; nf < 3; ++nf)
#pragma unroll
      for (int r = 0; r < 4; ++r) {
        int m = m0 + wr * 128 + mf * 16 + quad * 4 + r;
        int n = n0 + wc * 48 + nf * 16 + l15;
        C[(size_t)m * N + n] = f2bf(acc[mf][nf][r]);
      }
}

// ---------------------------------------------------------------------------
// 8-phase 128x256 NT GEMM (fp32 out). R4: grid 256 = 1 block/CU.
__global__ __launch_bounds__(512, 2) void gemm_nt_128x256(const unsigned short* __restrict__ A,
                                                          const unsigned short* __restrict__ BT,
                                                          float* __restrict__ C,
                                                          int M, int N, int K) {
  (void)M;
  __shared__ unsigned short As[2][128 * 64];
  __shared__ unsigned short Bs[2][256 * 64];
  const int nbn = N >> 8;
  const int nwg = gridDim.x;
  int wg = blockIdx.x;
  {  // XCD-aware swizzle (bijective: nwg % 8 == 0)
    int cpx = nwg >> 3;
    wg = (wg & 7) * cpx + (wg >> 3);
  }
  const int m0 = (wg / nbn) << 7;
  const int n0 = (wg % nbn) << 8;
  const int tid = threadIdx.x;
  const int lane = tid & 63, wave = tid >> 6;
  const int l15 = lane & 15, quad = lane >> 4;
  const int wr = wave >> 2, wc = wave & 3;   // 2 x 4 wave grid
  const int rA = wr * 64 + l15;              // + mf*16, mf in [0,4)
  const int rB = wc * 64 + l15;              // + nf*16, nf in [0,4)

  floatx4 acc[4][4];
#pragma unroll
  for (int i = 0; i < 4; ++i)
#pragma unroll
    for (int j = 0; j < 4; ++j) acc[i][j] = (floatx4){0.f, 0.f, 0.f, 0.f};

  const unsigned short* Ag = A + (size_t)m0 * K;
  const unsigned short* Bg = BT + (size_t)n0 * K;

  // B-half: 128 rows x 64k (16KB), 2 loads/thread.
  auto STAGE_B = [&](unsigned short* dst, const unsigned short* g, int h) {
#pragma unroll
    for (int j = 0; j < 2; ++j) {
      int idx = j * 512 + tid;
      int row = h * 128 + (idx >> 3);
      int cl = (idx & 7) ^ (row & 7);
      async16(dst + (size_t)h * 8192 + (size_t)idx * 8, g + (size_t)row * K + cl * 8);
    }
  };
  // A-half: 64 rows x 64k (8KB), 1 load/thread.
  auto STAGE_A = [&](unsigned short* dst, const unsigned short* g, int h) {
    int idx = tid;
    int row = h * 64 + (idx >> 3);
    int cl = (idx & 7) ^ (row & 7);
    async16(dst + (size_t)h * 4096 + (size_t)idx * 8, g + (size_t)row * K + cl * 8);
  };
  auto RD = [&](const unsigned short* buf, int row, int ks) -> short8 {
    int sc = ((ks << 2) + quad) ^ (row & 7);
    return *(const short8*)(buf + row * 64 + sc * 8);
  };

#define BAR() __builtin_amdgcn_s_barrier()
#define WAITL0() asm volatile("s_waitcnt lgkmcnt(0)" ::: "memory")

  // prologue: A(0) h0,h1 [2]; B(0) h0,h1 [4]; A(1) h0,h1 [2] = 8 loads/thread
  STAGE_A(As[0], Ag, 0); STAGE_A(As[0], Ag, 1);
  STAGE_B(Bs[0], Bg, 0); STAGE_B(Bs[0], Bg, 1);
  STAGE_A(As[1], Ag + 64, 0); STAGE_A(As[1], Ag + 64, 1);
  asm volatile("s_waitcnt vmcnt(2)" ::: "memory");   // tile0 landed; A(1) in flight
  BAR();

  const int NT = K >> 6;
  short8 a0[2][2], a1[2][2], b0[2][2], b1[2][2];
  for (int t = 0; t < NT; ++t) {
    const unsigned short* Ac = As[t & 1];
    const unsigned short* Bc = Bs[t & 1];
    unsigned short* Ast = As[t & 1];         // stage target: A(t+2), in-place
    unsigned short* Bst = Bs[(t + 1) & 1];   // stage target: B(t+1)

    // ---- phase 1: read a0 (mf0-1) + b0 (nf0-1) [8]; stage B(t+1)h0
#pragma unroll
    for (int mf = 0; mf < 2; ++mf)
#pragma unroll
      for (int ks = 0; ks < 2; ++ks) a0[mf][ks] = RD(Ac, rA + mf * 16, ks);
#pragma unroll
    for (int nf = 0; nf < 2; ++nf)
#pragma unroll
      for (int ks = 0; ks < 2; ++ks) b0[nf][ks] = RD(Bc, rB + nf * 16, ks);
    if (t + 1 < NT) STAGE_B(Bst, Bg + (size_t)(t + 1) * 64, 0);
    asm volatile("s_waitcnt lgkmcnt(4)" ::: "memory");
    BAR(); WAITL0();
    __builtin_amdgcn_s_setprio(1);
#pragma unroll
    for (int mf = 0; mf < 2; ++mf)
#pragma unroll
      for (int nf = 0; nf < 2; ++nf)
#pragma unroll
        for (int ks = 0; ks < 2; ++ks)
          acc[mf][nf] = __builtin_amdgcn_mfma_f32_16x16x32_bf16(a0[mf][ks], b0[nf][ks], acc[mf][nf], 0, 0, 0);
    __builtin_amdgcn_s_setprio(0);
    BAR();

    // ---- phase 2: read a1 (mf2-3) [4]; stage B(t+1)h1
#pragma unroll
    for (int mf = 0; mf < 2; ++mf)
#pragma unroll
      for (int ks = 0; ks < 2; ++ks) a1[mf][ks] = RD(Ac, rA + 32 + mf * 16, ks);
    if (t + 1 < NT) STAGE_B(Bst, Bg + (size_t)(t + 1) * 64, 1);
    BAR(); WAITL0();
    __builtin_amdgcn_s_setprio(1);
#pragma unroll
    for (int mf = 0; mf < 2; ++mf)
#pragma unroll
      for (int nf = 0; nf < 2; ++nf)
#pragma unroll
        for (int ks = 0; ks < 2; ++ks)
          acc[2 + mf][nf] = __builtin_amdgcn_mfma_f32_16x16x32_bf16(a1[mf][ks], b0[nf][ks], acc[2 + mf][nf], 0, 0, 0);
    __builtin_amdgcn_s_setprio(0);
    BAR();

    // ---- phase 3: read b1 (nf2-3) [4]; stage A(t+2)h0 (A(t) dead after ph2)
#pragma unroll
    for (int nf = 0; nf < 2; ++nf)
#pragma unroll
      for (int ks = 0; ks < 2; ++ks) b1[nf][ks] = RD(Bc, rB + 32 + nf * 16, ks);
    if (t + 2 < NT) STAGE_A(Ast, Ag + (size_t)(t + 2) * 64, 0);
    BAR(); WAITL0();
    __builtin_amdgcn_s_setprio(1);
#pragma unroll
    for (int mf = 0; mf < 2; ++mf)
#pragma unroll
      for (int nf = 0; nf < 2; ++nf)
#pragma unroll
        for (int ks = 0; ks < 2; ++ks)
          acc[2 + mf][2 + nf] = __builtin_amdgcn_mfma_f32_16x16x32_bf16(a1[mf][ks], b1[nf][ks], acc[2 + mf][2 + nf], 0, 0, 0);
    __builtin_amdgcn_s_setprio(0);
    BAR();

    // ---- phase 4: no reads; stage A(t+2)h1; counted vmcnt(2) per tile
    if (t + 2 < NT) {
      STAGE_A(Ast, Ag + (size_t)(t + 2) * 64, 1);
      asm volatile("s_waitcnt vmcnt(2)" ::: "memory");  // tile t+1 fully landed
    } else {
      asm volatile("s_waitcnt vmcnt(0)" ::: "memory");  // tail drain
    }
    BAR();
    __builtin_amdgcn_s_setprio(1);
#pragma unroll
    for (int mf = 0; mf < 2; ++mf)
#pragma unroll
      for (int nf = 0; nf < 2; ++nf)
#pragma unroll
        for (int ks = 0; ks < 2; ++ks)
          acc[mf][2 + nf] = __builtin_amdgcn_mfma_f32_16x16x32_bf16(a0[mf][ks], b1[nf][ks], acc[mf][2 + nf], 0, 0, 0);
    __builtin_amdgcn_s_setprio(0);
    BAR();
  }
#undef BAR
#undef WAITL0

#pragma unroll
  for (int mf = 0; mf < 4; ++mf)
#pragma unroll
    for (int nf = 0; nf < 4; ++nf)
#pragma unroll
      for (int r = 0; r < 4; ++r) {
        int m = m0 + wr * 64 + mf * 16 + quad * 4 + r;
        int n = n0 + wc * 64 + nf * 16 + l15;
        C[(size_t)m * N + n] = acc[mf][nf][r];
      }
}

// ---------------------------------------------------------------------------
// prep2: RMS-norm+RoPE AND V-transpose in ONE launch.
__global__ __launch_bounds__(256) void prep2(const unsigned short* __restrict__ qkv,
                                             const float* __restrict__ qw,
                                             const float* __restrict__ kw,
                                             unsigned short* __restrict__ qT,
                                             unsigned short* __restrict__ kT,
                                             unsigned short* __restrict__ vT) {
  const int S = 2048;
  __shared__ unsigned short tile[64][65];
  int bid = blockIdx.x;
  if (bid < 2048) {
    int wave = threadIdx.x >> 6, lane = threadIdx.x & 63;
    int wid0 = bid * 4 + wave;                   // [0,8192)
    float ifr = exp2f((float)lane * -0.2076205059304601f);
    const float qwl1 = qw[lane], qwl2 = qw[lane + 64];
    const float kwl1 = kw[lane], kwl2 = kw[lane + 64];
    for (int k = 0; k < 10; ++k) {
      int wid = wid0 + k * 8192;                 // [0,81920)
      int slot = wid % 20;
      int bs = wid / 20;
      int s = bs & (S - 1), b = bs >> 11;
      const unsigned short* src;
      unsigned short* dst;
      float w1, w2, scale;
      if (slot < 16) {
        src = qkv + (size_t)bs * 3072 + slot * 128;
        dst = qT + ((size_t)(b * 16 + slot) * S + s) * 128;
        w1 = qwl1; w2 = qwl2;
        scale = 0.08838834764831845f * 1.4426950408889634f;  // 1/sqrt(128)*log2(e)
      } else {
        int kvi = slot - 16;
        src = qkv + (size_t)bs * 3072 + 2048 + kvi * 128;
        dst = kT + ((size_t)(b * 4 + kvi) * S + s) * 128;
        w1 = kwl1; w2 = kwl2;
        scale = 1.0f;
      }
      float x1 = bf2f(src[lane]), x2 = bf2f(src[lane + 64]);
      float ss = x1 * x1 + x2 * x2;
#pragma unroll
      for (int m = 1; m < 64; m <<= 1) ss += __shfl_xor(ss, m, 64);
      float rms = rsqrtf(ss * (1.0f / 128.0f) + 1e-6f);
      float y1 = x1 * rms * w1;
      float y2 = x2 * rms * w2;
      float ang = (float)s * ifr;
      float c = cosf(ang), sn = sinf(ang);
      float o1 = (y1 * c - y2 * sn) * scale;
      float o2 = (y2 * c + y1 * sn) * scale;
      dst[lane] = f2bf(o1);
      dst[lane + 64] = f2bf(o2);
    }
    return;
  }
  bid -= 2048;
  // ---- V transpose: (B,S,KV,128) -> (B,KV,128,S)
  int dt = bid & 1, st = (bid >> 1) & 31, kv = (bid >> 6) & 3, b = bid >> 8;
  int s0 = st << 6, d0 = dt << 6;
  int i = threadIdx.x >> 2, cc = (threadIdx.x & 3) << 4;
  union { uint4 v[2]; unsigned short u[16]; } buf;
  const uint4* g = (const uint4*)(qkv + ((size_t)(b * S) + s0 + i) * 3072 + 2560 + kv * 128 + d0 + cc);
  buf.v[0] = g[0]; buf.v[1] = g[1];
#pragma unroll
  for (int j = 0; j < 16; ++j) tile[i][cc + j] = buf.u[j];
  __syncthreads();
#pragma unroll
  for (int j = 0; j < 16; ++j) buf.u[j] = tile[cc + j][i];
  uint4* o = (uint4*)(vT + ((size_t)(b * 4 + kv) * 128 + d0 + i) * S + s0 + cc);
  o[0] = buf.v[0]; o[1] = buf.v[1];
}

// ---------------------------------------------------------------------------
// MFMA flash attention v3, non-causal. R9: 256 q-rows per block, 8 waves x 32
// rows, grid = 2x16x8 = 256 = 1 block/CU. Per-wave inner structure identical
// to the proven R6 kernel; only geometry changed. Wins: K/V staging bytes and
// async16 count per unit work HALVE (8 waves share one 64-key tile vs two
// 128-row blocks each streaming K/V); chunked XCD swizzle puts all 32 blocks
// of one (b,kv) group on one XCD (K+V = 1MB -> L2-resident). LDS 96KB.
__global__ __launch_bounds__(512, 2) void flash_attn(const unsigned short* __restrict__ qT,
                                                     const unsigned short* __restrict__ kT,
                                                     const unsigned short* __restrict__ vT,
                                                     unsigned short* __restrict__ ao) {
  const int S = 2048;
  int wg = blockIdx.x;
  {  // XCD swizzle: consecutive wg share (b,kv) -> same XCD (nwg=256, %8==0)
    wg = (wg & 7) * 32 + (wg >> 3);
  }
  int qt = wg & 7, h = (wg >> 3) & 15, b = wg >> 7;
  int kv = h >> 2;
  int tid = threadIdx.x;
  int lane = tid & 63, wave = tid >> 6;    // wave in [0,8)
  int l15 = lane & 15, quad = lane >> 4;

  __shared__ unsigned short Ks[2][64 * 128];   // keys x dh, 16 chunks/row, XOR swizzled
  __shared__ unsigned short VTs[2][128 * 64];  // d x keys, 8 chunks/row, XOR swizzled
  __shared__ unsigned short Ps[8][32 * 64];    // per-wave P in PV-A layout, swizzled
  unsigned short* Psw = Ps[wave];

  // Q fragments (B-operand of S^T: B[n=qrow][k=dh]), register-resident
  short8 bq[2][4];
  const unsigned short* qbase = qT + ((size_t)(b * 16 + h) * S + qt * 256 + wave * 32) * 128;
#pragma unroll
  for (int nt = 0; nt < 2; ++nt)
#pragma unroll
    for (int kk = 0; kk < 4; ++kk)
      bq[nt][kk] = *(const short8*)(qbase + (size_t)(nt * 16 + l15) * 128 + kk * 32 + quad * 8);

  floatx4 O[2][8];
#pragma unroll
  for (int mt = 0; mt < 2; ++mt)
#pragma unroll
    for (int dt = 0; dt < 8; ++dt) O[mt][dt] = (floatx4){0.f, 0.f, 0.f, 0.f};
  float l_acc[2] = {0.f, 0.f};

  const size_t kbase = (size_t)(b * 4 + kv) * S * 128;
  const size_t vbase = (size_t)(b * 4 + kv) * 128 * S;

  // prefetch tile 0 into buffer 0 (2 K + 2 V async16/thread; 512 threads)
#pragma unroll
  for (int i = 0; i < 2; ++i) {
    int Lc = (wave * 2 + i) * 64 + lane;       // [0,1024)
    int row = Lc >> 4, cjk = (lane & 15) ^ (row & 7);
    async16(Ks[0] + (size_t)Lc * 8, kT + kbase + (size_t)row * 128 + cjk * 8);
    int d = Lc >> 3, cjv = (lane & 7) ^ (d & 7);
    async16(VTs[0] + (size_t)Lc * 8, vT + vbase + (size_t)d * S + cjv * 8);
  }

  for (int kt = 0; kt < 32; ++kt) {
    int cur = kt & 1;
    __syncthreads();  // drains prefetch for tile kt; fences reads of buf cur^1 (kt-1)
    if (kt + 1 < 32) {
#pragma unroll
      for (int i = 0; i < 2; ++i) {
        int Lc = (wave * 2 + i) * 64 + lane;
        int row = Lc >> 4, cjk = (lane & 15) ^ (row & 7);
        async16(Ks[cur ^ 1] + (size_t)Lc * 8,
                kT + kbase + (size_t)((kt + 1) * 64 + row) * 128 + cjk * 8);
        int d = Lc >> 3, cjv = (lane & 7) ^ (d & 7);
        async16(VTs[cur ^ 1] + (size_t)Lc * 8,
                vT + vbase + (size_t)d * S + (kt + 1) * 64 + cjv * 8);
      }
    }

    // S^T = K * Q^T : C[m=key][n=qrow]
    floatx4 st[4][2];
#pragma unroll
    for (int a = 0; a < 4; ++a)
#pragma unroll
      for (int nt = 0; nt < 2; ++nt) st[a][nt] = (floatx4){0.f, 0.f, 0.f, 0.f};
    __builtin_amdgcn_s_setprio(1);
#pragma unroll
    for (int kk = 0; kk < 4; ++kk)
#pragma unroll
      for (int a = 0; a < 4; ++a) {
        int m = a * 16 + l15;
        short8 ak = *(const short8*)(&Ks[cur][(m * 16 + ((kk * 4 + quad) ^ (m & 7))) * 8]);
#pragma unroll
        for (int nt = 0; nt < 2; ++nt)
          st[a][nt] = __builtin_amdgcn_mfma_f32_16x16x32_bf16(ak, bq[nt][kk], st[a][nt], 0, 0, 0);
      }
    __builtin_amdgcn_s_setprio(0);

    // P = exp2(S^T); pack to bf16 into per-wave Ps (PV-A layout); l partials per lane.
#pragma unroll
    for (int nt = 0; nt < 2; ++nt) {
      int m = nt * 16 + l15;
#pragma unroll
      for (int a = 0; a < 4; ++a) {
        float e0 = __builtin_amdgcn_exp2f(st[a][nt][0]);
        float e1 = __builtin_amdgcn_exp2f(st[a][nt][1]);
        float e2 = __builtin_amdgcn_exp2f(st[a][nt][2]);
        float e3 = __builtin_amdgcn_exp2f(st[a][nt][3]);
        l_acc[nt] += (e0 + e1) + (e2 + e3);
        u32 p01 = __builtin_amdgcn_perm(fbits(e1) + 0x8000u, fbits(e0) + 0x8000u, 0x07060302u);
        u32 p23 = __builtin_amdgcn_perm(fbits(e3) + 0x8000u, fbits(e2) + 0x8000u, 0x07060302u);
        int c = (a * 2 + (quad >> 1)) ^ (m & 7);
        uint2 pk; pk.x = p01; pk.y = p23;
        *(uint2*)(&Psw[(m * 8 + c) * 8 + (quad & 1) * 4]) = pk;
      }
    }

    // PV: O[m=qrow][n=d] += P[m][key] * VT[n][key]
    __builtin_amdgcn_s_setprio(1);
#pragma unroll
    for (int kk2 = 0; kk2 < 2; ++kk2) {
      short8 ap[2];
#pragma unroll
      for (int mt = 0; mt < 2; ++mt) {
        int m = mt * 16 + l15;
        ap[mt] = *(const short8*)(&Psw[(m * 8 + ((kk2 * 4 + quad) ^ (m & 7))) * 8]);
      }
#pragma unroll
      for (int dt = 0; dt < 8; ++dt) {
        int n = dt * 16 + l15;
        short8 bv = *(const short8*)(&VTs[cur][(n * 8 + ((kk2 * 4 + quad) ^ (n & 7))) * 8]);
#pragma unroll
        for (int mt = 0; mt < 2; ++mt)
          O[mt][dt] = __builtin_amdgcn_mfma_f32_16x16x32_bf16(ap[mt], bv, O[mt][dt], 0, 0, 0);
      }
    }
    __builtin_amdgcn_s_setprio(0);
  }

  // epilogue: reduce l across quads, normalize, store
  float linv[2];
#pragma unroll
  for (int nt = 0; nt < 2; ++nt) {
    float l = l_acc[nt];
    l += __shfl_xor(l, 16, 64);
    l += __shfl_xor(l, 32, 64);
    linv[nt] = 1.f / l;
  }
#pragma unroll
  for (int mt = 0; mt < 2; ++mt)
#pragma unroll
    for (int r = 0; r < 4; ++r) {
      float inv = __shfl(linv[mt], quad * 4 + r, 64);
      int s = qt * 256 + wave * 32 + mt * 16 + quad * 4 + r;
#pragma unroll
      for (int dt = 0; dt < 8; ++dt) {
        int d = dt * 16 + l15;
        ao[((size_t)(b * S + s) * 16 + h) * 128 + d] = f2bf(O[mt][dt][r] * inv);
      }
    }
}

// ---------------------------------------------------------------------------
extern "C" void kernel_launch(void* const* d_in, const int* in_sizes, int n_in,
                              void* d_out, int out_size, void* d_ws, size_t ws_size,
                              hipStream_t stream) {
  const float* x  = (const float*)d_in[0];
  const float* Wq = (const float*)d_in[1];
  const float* Wk = (const float*)d_in[2];
  const float* Wv = (const float*)d_in[3];
  const float* Wo = (const float*)d_in[4];
  const float* qw = (const float*)d_in[5];
  const float* kw = (const float*)d_in[6];
  float* out = (float*)d_out;

  unsigned short* p = (unsigned short*)d_ws;
  unsigned short* xbf   = p; p += (size_t)4096 * 2048;
  unsigned short* WTqkv = p; p += (size_t)3072 * 2048;
  unsigned short* WoT   = p; p += (size_t)2048 * 2048;
  unsigned short* qkv   = p; p += (size_t)4096 * 3072;
  unsigned short* qTb   = p; p += (size_t)2 * 16 * 2048 * 128;
  unsigned short* kTb   = p; p += (size_t)2 * 4 * 2048 * 128;
  unsigned short* vTb   = p; p += (size_t)2 * 4 * 2048 * 128;
  unsigned short* ao    = p; p += (size_t)4096 * 2048;

  // fused preprocessing: x-convert || weight transposes
  prep1<<<6656, 256, 0, stream>>>(x, Wq, Wk, Wv, Wo, xbf, WTqkv, WoT);

  // qkv projection: 8-phase 256x192 -> 16 x 16 = 256 blocks = 1 per CU
  gemm_nt_256x192<<<256, 512, 0, stream>>>(xbf, WTqkv, qkv, 4096, 3072, 2048);

  // fused: norm+rope || v-transpose
  prep2<<<2560, 256, 0, stream>>>(qkv, qw, kw, qTb, kTb, vTb);

  // flash: 256 q-rows/block, 8 waves, grid 256 = 1 block/CU
  flash_attn<<<256, 512, 0, stream>>>(qTb, kTb, vTb, ao);

  // output projection: 8-phase 128x256 -> 32 x 8 = 256 blocks = 1 per CU
  gemm_nt_128x256<<<256, 512, 0, stream>>>(ao, WoT, out, 4096, 2048, 2048);
}

// Round 11
// 307.379 us; speedup vs baseline: 1.0338x; 1.0338x over previous
//
#include <hip/hip_runtime.h>
#include <stdint.h>

#define LOG2E 1.4426950408889634f

typedef __attribute__((ext_vector_type(8))) short short8;
typedef __attribute__((ext_vector_type(4))) float floatx4;
typedef unsigned int u32;

__device__ __forceinline__ float bf2f(unsigned short h) {
  union { unsigned int u; float f; } v; v.u = ((unsigned int)h) << 16; return v.f;
}
__device__ __forceinline__ unsigned short f2bf(float f) {
  union { float f; unsigned int u; } v; v.f = f;
  unsigned int r = v.u + 0x7FFFu + ((v.u >> 16) & 1u);
  return (unsigned short)(r >> 16);
}
__device__ __forceinline__ u32 fbits(float f) {
  union { float f; u32 u; } v; v.f = f; return v.u;
}
// async global->LDS, 16B per lane. dst must be wave-contiguous (base + lane*16).
__device__ __forceinline__ void async16(void* lds, const void* g) {
  __builtin_amdgcn_global_load_lds((const __attribute__((address_space(1))) u32*)g,
                                   (__attribute__((address_space(3))) u32*)lds, 16, 0, 0);
}

// ---------------------------------------------------------------------------
// prep1: fp32->bf16 x-convert, all 4 weight transposes, AND RoPE cos/sin
// table fill in ONE launch. Blocks [0,4096): x cvt; [4096,6656): W transpose;
// [6656,7168): rope table — 512 blocks x 4 s-rows = 2048 rows x 64 j float2
// (1MB, L2-resident). R10 FAILED because only 256 table blocks were launched
// (covered s<1024; s>=1024 read garbage, absmax 0.13). 512 blocks covers S.
__global__ __launch_bounds__(256) void prep1(const float* __restrict__ x,
                                             const float* __restrict__ Wq,
                                             const float* __restrict__ Wk,
                                             const float* __restrict__ Wv,
                                             const float* __restrict__ Wo,
                                             unsigned short* __restrict__ xbf,
                                             unsigned short* __restrict__ WTqkv,
                                             unsigned short* __restrict__ WoT,
                                             float2* __restrict__ rope_tab) {
  __shared__ unsigned short tile[64][65];
  int bid = blockIdx.x;
  if (bid < 4096) {
    int i = (bid * 256 + threadIdx.x) * 8;
    float4 a = ((const float4*)(x + i))[0];
    float4 b = ((const float4*)(x + i))[1];
    union { uint4 v; unsigned short u[8]; } o;
    o.u[0] = f2bf(a.x); o.u[1] = f2bf(a.y); o.u[2] = f2bf(a.z); o.u[3] = f2bf(a.w);
    o.u[4] = f2bf(b.x); o.u[5] = f2bf(b.y); o.u[6] = f2bf(b.z); o.u[7] = f2bf(b.w);
    *(uint4*)(xbf + i) = o.v;
    return;
  }
  if (bid >= 6656) {
    // RoPE table: 512 blocks x (4 s-rows x 64 j) = full S=2048
    int t = (bid - 6656) * 4 + (threadIdx.x >> 6);
    int j = threadIdx.x & 63;
    float ang = (float)t * exp2f((float)j * -0.2076205059304601f);
    rope_tab[(t << 6) + j] = make_float2(cosf(ang), sinf(ang));
    return;
  }
  bid -= 4096;
  const int R = 2048;
  const float* src; unsigned short* dst; int C;
  if (bid < 1024) { src = Wq; dst = WTqkv; C = 2048; }
  else if (bid < 1280) { src = Wk; dst = WTqkv + (size_t)2048 * 2048; C = 512; bid -= 1024; }
  else if (bid < 1536) { src = Wv; dst = WTqkv + (size_t)2048 * 2048 + (size_t)512 * 2048; C = 512; bid -= 1280; }
  else { src = Wo; dst = WoT; C = 2048; bid -= 1536; }

  int tc = C >> 6;
  int br = bid / tc, bc = bid % tc;
  int r0 = br << 6, c0 = bc << 6;
  int i = threadIdx.x >> 2, cc = (threadIdx.x & 3) << 4;
  const float4* g = (const float4*)(src + (size_t)(r0 + i) * C + c0 + cc);
  float4 f0 = g[0], f1 = g[1], f2 = g[2], f3 = g[3];
  unsigned short u[16];
  u[0]=f2bf(f0.x); u[1]=f2bf(f0.y); u[2]=f2bf(f0.z); u[3]=f2bf(f0.w);
  u[4]=f2bf(f1.x); u[5]=f2bf(f1.y); u[6]=f2bf(f1.z); u[7]=f2bf(f1.w);
  u[8]=f2bf(f2.x); u[9]=f2bf(f2.y); u[10]=f2bf(f2.z); u[11]=f2bf(f2.w);
  u[12]=f2bf(f3.x); u[13]=f2bf(f3.y); u[14]=f2bf(f3.z); u[15]=f2bf(f3.w);
#pragma unroll
  for (int j = 0; j < 16; ++j) tile[i][cc + j] = u[j];
  __syncthreads();
  union { uint4 v[2]; unsigned short u[16]; } buf;
#pragma unroll
  for (int j = 0; j < 16; ++j) buf.u[j] = tile[cc + j][i];
  uint4* o = (uint4*)(dst + (size_t)(c0 + i) * R + r0 + cc);
  o[0] = buf.v[0]; o[1] = buf.v[1];
}

// ---------------------------------------------------------------------------
// 8-phase 256x192 NT GEMM, bf16 out — qkv projection. R6: 256 blocks = 1/CU.
__global__ __launch_bounds__(512, 2) void gemm_nt_256x192(const unsigned short* __restrict__ A,
                                                          const unsigned short* __restrict__ BT,
                                                          unsigned short* __restrict__ C,
                                                          int M, int N, int K) {
  (void)M;
  __shared__ unsigned short As[2][256 * 64];
  __shared__ unsigned short Bs[2][192 * 64];
  const int nbn = N / 192;
  const int nwg = gridDim.x;
  int wg = blockIdx.x;
  {  // XCD-aware swizzle (bijective: nwg % 8 == 0)
    int cpx = nwg >> 3;
    wg = (wg & 7) * cpx + (wg >> 3);
  }
  const int m0 = (wg / nbn) << 8;
  const int n0 = (wg % nbn) * 192;
  const int tid = threadIdx.x;
  const int lane = tid & 63, wave = tid >> 6;
  const int l15 = lane & 15, quad = lane >> 4;
  const int wr = wave >> 2, wc = wave & 3;   // 2 x 4 wave grid
  const int rA = wr * 128 + l15;             // + mf*16, mf in [0,8)
  const int rB = wc * 48 + l15;              // + nf*16, nf in [0,3)

  floatx4 acc[8][3];
#pragma unroll
  for (int i = 0; i < 8; ++i)
#pragma unroll
    for (int j = 0; j < 3; ++j) acc[i][j] = (floatx4){0.f, 0.f, 0.f, 0.f};

  const unsigned short* Ag = A + (size_t)m0 * K;
  const unsigned short* Bg = BT + (size_t)n0 * K;

  // A row-half h (128 rows x 64k = 16KB): 2 loads/thread.
  auto STAGE_A = [&](unsigned short* dst, const unsigned short* g, int h) {
#pragma unroll
    for (int j = 0; j < 2; ++j) {
      int idx = j * 512 + tid;              // [0,1024)
      int row = h * 128 + (idx >> 3);
      int cl = (idx & 7) ^ (row & 7);
      async16(dst + (size_t)h * 8192 + (size_t)idx * 8, g + (size_t)row * K + cl * 8);
    }
  };
  // B full tile (192 rows x 64k = 24KB): 3 loads/thread.
  auto STAGE_B = [&](unsigned short* dst, const unsigned short* g) {
#pragma unroll
    for (int j = 0; j < 3; ++j) {
      int idx = j * 512 + tid;              // [0,1536)
      int row = idx >> 3;
      int cl = (idx & 7) ^ (row & 7);
      async16(dst + (size_t)idx * 8, g + (size_t)row * K + cl * 8);
    }
  };
  auto RD = [&](const unsigned short* buf, int row, int ks) -> short8 {
    int sc = ((ks << 2) + quad) ^ (row & 7);
    return *(const short8*)(buf + row * 64 + sc * 8);
  };

#define BAR() __builtin_amdgcn_s_barrier()
#define WAITL0() asm volatile("s_waitcnt lgkmcnt(0)" ::: "memory")

  // prologue: A(0) h0,h1 [4]; B(0) [3]; A(1) h0,h1 [4] = 11 loads/thread
  STAGE_A(As[0], Ag, 0); STAGE_A(As[0], Ag, 1);
  STAGE_B(Bs[0], Bg);
  STAGE_A(As[1], Ag + 64, 0); STAGE_A(As[1], Ag + 64, 1);
  asm volatile("s_waitcnt vmcnt(4)" ::: "memory");   // tile0 landed; A(1) in flight
  BAR();

  const int NT = K >> 6;
  short8 a0[4][2], a1[4][2], b0[2][2], b1[2];
  for (int t = 0; t < NT; ++t) {
    const unsigned short* Ac = As[t & 1];
    const unsigned short* Bc = Bs[t & 1];
    unsigned short* Ast = As[t & 1];         // stage target: A(t+2), in-place
    unsigned short* Bst = Bs[(t + 1) & 1];   // stage target: B(t+1)

    // ---- phase 1: read a0 (mf0-3) + b0 (nf0-1) [12]; stage B(t+1) full [3]
#pragma unroll
    for (int mf = 0; mf < 4; ++mf)
#pragma unroll
      for (int ks = 0; ks < 2; ++ks) a0[mf][ks] = RD(Ac, rA + mf * 16, ks);
#pragma unroll
    for (int nf = 0; nf < 2; ++nf)
#pragma unroll
      for (int ks = 0; ks < 2; ++ks) b0[nf][ks] = RD(Bc, rB + nf * 16, ks);
    if (t + 1 < NT) STAGE_B(Bst, Bg + (size_t)(t + 1) * 64);
    asm volatile("s_waitcnt lgkmcnt(8)" ::: "memory");
    BAR(); WAITL0();
    __builtin_amdgcn_s_setprio(1);
#pragma unroll
    for (int mf = 0; mf < 4; ++mf)
#pragma unroll
      for (int nf = 0; nf < 2; ++nf)
#pragma unroll
        for (int ks = 0; ks < 2; ++ks)
          acc[mf][nf] = __builtin_amdgcn_mfma_f32_16x16x32_bf16(a0[mf][ks], b0[nf][ks], acc[mf][nf], 0, 0, 0);
    __builtin_amdgcn_s_setprio(0);
    BAR();

    // ---- phase 2: read a1 (mf4-7) [8]
#pragma unroll
    for (int mf = 0; mf < 4; ++mf)
#pragma unroll
      for (int ks = 0; ks < 2; ++ks) a1[mf][ks] = RD(Ac, rA + 64 + mf * 16, ks);
    BAR(); WAITL0();
    __builtin_amdgcn_s_setprio(1);
#pragma unroll
    for (int mf = 0; mf < 4; ++mf)
#pragma unroll
      for (int nf = 0; nf < 2; ++nf)
#pragma unroll
        for (int ks = 0; ks < 2; ++ks)
          acc[4 + mf][nf] = __builtin_amdgcn_mfma_f32_16x16x32_bf16(a1[mf][ks], b0[nf][ks], acc[4 + mf][nf], 0, 0, 0);
    __builtin_amdgcn_s_setprio(0);
    BAR();

    // ---- phase 3: read b1 (nf2) [2]; stage A(t+2)h0 (A(t) dead after ph2)
#pragma unroll
    for (int ks = 0; ks < 2; ++ks) b1[ks] = RD(Bc, rB + 32, ks);
    if (t + 2 < NT) STAGE_A(Ast, Ag + (size_t)(t + 2) * 64, 0);
    BAR(); WAITL0();
    __builtin_amdgcn_s_setprio(1);
#pragma unroll
    for (int mf = 0; mf < 4; ++mf)
#pragma unroll
      for (int ks = 0; ks < 2; ++ks)
        acc[4 + mf][2] = __builtin_amdgcn_mfma_f32_16x16x32_bf16(a1[mf][ks], b1[ks], acc[4 + mf][2], 0, 0, 0);
    __builtin_amdgcn_s_setprio(0);
    BAR();

    // ---- phase 4: stage A(t+2)h1; counted vmcnt(4) per tile
    if (t + 2 < NT) {
      STAGE_A(Ast, Ag + (size_t)(t + 2) * 64, 1);
      asm volatile("s_waitcnt vmcnt(4)" ::: "memory");  // tile t+1 fully landed
    } else {
      asm volatile("s_waitcnt vmcnt(0)" ::: "memory");  // tail drain
    }
    BAR();
    __builtin_amdgcn_s_setprio(1);
#pragma unroll
    for (int mf = 0; mf < 4; ++mf)
#pragma unroll
      for (int ks = 0; ks < 2; ++ks)
        acc[mf][2] = __builtin_amdgcn_mfma_f32_16x16x32_bf16(a0[mf][ks], b1[ks], acc[mf][2], 0, 0, 0);
    __builtin_amdgcn_s_setprio(0);
    BAR();
  }
#undef BAR
#undef WAITL0

#pragma unroll
  for (int mf = 0; mf < 8; ++mf)
#pragma unroll
    for (int nf = 0; nf < 3; ++nf)
#pragma unroll
      for (int r = 0; r < 4; ++r) {
        int m = m0 + wr * 128 + mf * 16 + quad * 4 + r;
        int n = n0 + wc * 48 + nf * 16 + l15;
        C[(size_t)m * N + n] = f2bf(acc[mf][nf][r]);
      }
}

// ---------------------------------------------------------------------------
// 8-phase 128x256 NT GEMM (fp32 out). R4: grid 256 = 1 block/CU.
__global__ __launch_bounds__(512, 2) void gemm_nt_128x256(const unsigned short* __restrict__ A,
                                                          const unsigned short* __restrict__ BT,
                                                          float* __restrict__ C,
                                                          int M, int N, int K) {
  (void)M;
  __shared__ unsigned short As[2][128 * 64];
  __shared__ unsigned short Bs[2][256 * 64];
  const int nbn = N >> 8;
  const int nwg = gridDim.x;
  int wg = blockIdx.x;
  {  // XCD-aware swizzle (bijective: nwg % 8 == 0)
    int cpx = nwg >> 3;
    wg = (wg & 7) * cpx + (wg >> 3);
  }
  const int m0 = (wg / nbn) << 7;
  const int n0 = (wg % nbn) << 8;
  const int tid = threadIdx.x;
  const int lane = tid & 63, wave = tid >> 6;
  const int l15 = lane & 15, quad = lane >> 4;
  const int wr = wave >> 2, wc = wave & 3;   // 2 x 4 wave grid
  const int rA = wr * 64 + l15;              // + mf*16, mf in [0,4)
  const int rB = wc * 64 + l15;              // + nf*16, nf in [0,4)

  floatx4 acc[4][4];
#pragma unroll
  for (int i = 0; i < 4; ++i)
#pragma unroll
    for (int j = 0; j < 4; ++j) acc[i][j] = (floatx4){0.f, 0.f, 0.f, 0.f};

  const unsigned short* Ag = A + (size_t)m0 * K;
  const unsigned short* Bg = BT + (size_t)n0 * K;

  // B-half: 128 rows x 64k (16KB), 2 loads/thread.
  auto STAGE_B = [&](unsigned short* dst, const unsigned short* g, int h) {
#pragma unroll
    for (int j = 0; j < 2; ++j) {
      int idx = j * 512 + tid;
      int row = h * 128 + (idx >> 3);
      int cl = (idx & 7) ^ (row & 7);
      async16(dst + (size_t)h * 8192 + (size_t)idx * 8, g + (size_t)row * K + cl * 8);
    }
  };
  // A-half: 64 rows x 64k (8KB), 1 load/thread.
  auto STAGE_A = [&](unsigned short* dst, const unsigned short* g, int h) {
    int idx = tid;
    int row = h * 64 + (idx >> 3);
    int cl = (idx & 7) ^ (row & 7);
    async16(dst + (size_t)h * 4096 + (size_t)idx * 8, g + (size_t)row * K + cl * 8);
  };
  auto RD = [&](const unsigned short* buf, int row, int ks) -> short8 {
    int sc = ((ks << 2) + quad) ^ (row & 7);
    return *(const short8*)(buf + row * 64 + sc * 8);
  };

#define BAR() __builtin_amdgcn_s_barrier()
#define WAITL0() asm volatile("s_waitcnt lgkmcnt(0)" ::: "memory")

  // prologue: A(0) h0,h1 [2]; B(0) h0,h1 [4]; A(1) h0,h1 [2] = 8 loads/thread
  STAGE_A(As[0], Ag, 0); STAGE_A(As[0], Ag, 1);
  STAGE_B(Bs[0], Bg, 0); STAGE_B(Bs[0], Bg, 1);
  STAGE_A(As[1], Ag + 64, 0); STAGE_A(As[1], Ag + 64, 1);
  asm volatile("s_waitcnt vmcnt(2)" ::: "memory");   // tile0 landed; A(1) in flight
  BAR();

  const int NT = K >> 6;
  short8 a0[2][2], a1[2][2], b0[2][2], b1[2][2];
  for (int t = 0; t < NT; ++t) {
    const unsigned short* Ac = As[t & 1];
    const unsigned short* Bc = Bs[t & 1];
    unsigned short* Ast = As[t & 1];         // stage target: A(t+2), in-place
    unsigned short* Bst = Bs[(t + 1) & 1];   // stage target: B(t+1)

    // ---- phase 1: read a0 (mf0-1) + b0 (nf0-1) [8]; stage B(t+1)h0
#pragma unroll
    for (int mf = 0; mf < 2; ++mf)
#pragma unroll
      for (int ks = 0; ks < 2; ++ks) a0[mf][ks] = RD(Ac, rA + mf * 16, ks);
#pragma unroll
    for (int nf = 0; nf < 2; ++nf)
#pragma unroll
      for (int ks = 0; ks < 2; ++ks) b0[nf][ks] = RD(Bc, rB + nf * 16, ks);
    if (t + 1 < NT) STAGE_B(Bst, Bg + (size_t)(t + 1) * 64, 0);
    asm volatile("s_waitcnt lgkmcnt(4)" ::: "memory");
    BAR(); WAITL0();
    __builtin_amdgcn_s_setprio(1);
#pragma unroll
    for (int mf = 0; mf < 2; ++mf)
#pragma unroll
      for (int nf = 0; nf < 2; ++nf)
#pragma unroll
        for (int ks = 0; ks < 2; ++ks)
          acc[mf][nf] = __builtin_amdgcn_mfma_f32_16x16x32_bf16(a0[mf][ks], b0[nf][ks], acc[mf][nf], 0, 0, 0);
    __builtin_amdgcn_s_setprio(0);
    BAR();

    // ---- phase 2: read a1 (mf2-3) [4]; stage B(t+1)h1
#pragma unroll
    for (int mf = 0; mf < 2; ++mf)
#pragma unroll
      for (int ks = 0; ks < 2; ++ks) a1[mf][ks] = RD(Ac, rA + 32 + mf * 16, ks);
    if (t + 1 < NT) STAGE_B(Bst, Bg + (size_t)(t + 1) * 64, 1);
    BAR(); WAITL0();
    __builtin_amdgcn_s_setprio(1);
#pragma unroll
    for (int mf = 0; mf < 2; ++mf)
#pragma unroll
      for (int nf = 0; nf < 2; ++nf)
#pragma unroll
        for (int ks = 0; ks < 2; ++ks)
          acc[2 + mf][nf] = __builtin_amdgcn_mfma_f32_16x16x32_bf16(a1[mf][ks], b0[nf][ks], acc[2 + mf][nf], 0, 0, 0);
    __builtin_amdgcn_s_setprio(0);
    BAR();

    // ---- phase 3: read b1 (nf2-3) [4]; stage A(t+2)h0 (A(t) dead after ph2)
#pragma unroll
    for (int nf = 0; nf < 2; ++nf)
#pragma unroll
      for (int ks = 0; ks < 2; ++ks) b1[nf][ks] = RD(Bc, rB + 32 + nf * 16, ks);
    if (t + 2 < NT) STAGE_A(Ast, Ag + (size_t)(t + 2) * 64, 0);
    BAR(); WAITL0();
    __builtin_amdgcn_s_setprio(1);
#pragma unroll
    for (int mf = 0; mf < 2; ++mf)
#pragma unroll
      for (int nf = 0; nf < 2; ++nf)
#pragma unroll
        for (int ks = 0; ks < 2; ++ks)
          acc[2 + mf][2 + nf] = __builtin_amdgcn_mfma_f32_16x16x32_bf16(a1[mf][ks], b1[nf][ks], acc[2 + mf][2 + nf], 0, 0, 0);
    __builtin_amdgcn_s_setprio(0);
    BAR();

    // ---- phase 4: no reads; stage A(t+2)h1; counted vmcnt(2) per tile
    if (t + 2 < NT) {
      STAGE_A(Ast, Ag + (size_t)(t + 2) * 64, 1);
      asm volatile("s_waitcnt vmcnt(2)" ::: "memory");  // tile t+1 fully landed
    } else {
      asm volatile("s_waitcnt vmcnt(0)" ::: "memory");  // tail drain
    }
    BAR();
    __builtin_amdgcn_s_setprio(1);
#pragma unroll
    for (int mf = 0; mf < 2; ++mf)
#pragma unroll
      for (int nf = 0; nf < 2; ++nf)
#pragma unroll
        for (int ks = 0; ks < 2; ++ks)
          acc[mf][2 + nf] = __builtin_amdgcn_mfma_f32_16x16x32_bf16(a0[mf][ks], b1[nf][ks], acc[mf][2 + nf], 0, 0, 0);
    __builtin_amdgcn_s_setprio(0);
    BAR();
  }
#undef BAR
#undef WAITL0

#pragma unroll
  for (int mf = 0; mf < 4; ++mf)
#pragma unroll
    for (int nf = 0; nf < 4; ++nf)
#pragma unroll
      for (int r = 0; r < 4; ++r) {
        int m = m0 + wr * 64 + mf * 16 + quad * 4 + r;
        int n = n0 + wc * 64 + nf * 16 + l15;
        C[(size_t)m * N + n] = acc[mf][nf][r];
      }
}

// ---------------------------------------------------------------------------
// prep2: RMS-norm+RoPE AND V-transpose in ONE launch. R11: cos/sin from the
// prep1-filled table (one coalesced 8B load/lane/slot) instead of per-slot
// sinf/cosf — removes 81920x64x2 trig ops from the hot loop.
__global__ __launch_bounds__(256) void prep2(const unsigned short* __restrict__ qkv,
                                             const float* __restrict__ qw,
                                             const float* __restrict__ kw,
                                             const float2* __restrict__ rope_tab,
                                             unsigned short* __restrict__ qT,
                                             unsigned short* __restrict__ kT,
                                             unsigned short* __restrict__ vT) {
  const int S = 2048;
  __shared__ unsigned short tile[64][65];
  int bid = blockIdx.x;
  if (bid < 2048) {
    int wave = threadIdx.x >> 6, lane = threadIdx.x & 63;
    int wid0 = bid * 4 + wave;                   // [0,8192)
    const float qwl1 = qw[lane], qwl2 = qw[lane + 64];
    const float kwl1 = kw[lane], kwl2 = kw[lane + 64];
    for (int k = 0; k < 10; ++k) {
      int wid = wid0 + k * 8192;                 // [0,81920)
      int slot = wid % 20;
      int bs = wid / 20;
      int s = bs & (S - 1), b = bs >> 11;
      const unsigned short* src;
      unsigned short* dst;
      float w1, w2, scale;
      if (slot < 16) {
        src = qkv + (size_t)bs * 3072 + slot * 128;
        dst = qT + ((size_t)(b * 16 + slot) * S + s) * 128;
        w1 = qwl1; w2 = qwl2;
        scale = 0.08838834764831845f * 1.4426950408889634f;  // 1/sqrt(128)*log2(e)
      } else {
        int kvi = slot - 16;
        src = qkv + (size_t)bs * 3072 + 2048 + kvi * 128;
        dst = kT + ((size_t)(b * 4 + kvi) * S + s) * 128;
        w1 = kwl1; w2 = kwl2;
        scale = 1.0f;
      }
      float x1 = bf2f(src[lane]), x2 = bf2f(src[lane + 64]);
      float ss = x1 * x1 + x2 * x2;
#pragma unroll
      for (int m = 1; m < 64; m <<= 1) ss += __shfl_xor(ss, m, 64);
      float rms = rsqrtf(ss * (1.0f / 128.0f) + 1e-6f);
      float y1 = x1 * rms * w1;
      float y2 = x2 * rms * w2;
      float2 cs = rope_tab[(s << 6) + lane];
      float c = cs.x, sn = cs.y;
      float o1 = (y1 * c - y2 * sn) * scale;
      float o2 = (y2 * c + y1 * sn) * scale;
      dst[lane] = f2bf(o1);
      dst[lane + 64] = f2bf(o2);
    }
    return;
  }
  bid -= 2048;
  // ---- V transpose: (B,S,KV,128) -> (B,KV,128,S)
  int dt = bid & 1, st = (bid >> 1) & 31, kv = (bid >> 6) & 3, b = bid >> 8;
  int s0 = st << 6, d0 = dt << 6;
  int i = threadIdx.x >> 2, cc = (threadIdx.x & 3) << 4;
  union { uint4 v[2]; unsigned short u[16]; } buf;
  const uint4* g = (const uint4*)(qkv + ((size_t)(b * S) + s0 + i) * 3072 + 2560 + kv * 128 + d0 + cc);
  buf.v[0] = g[0]; buf.v[1] = g[1];
#pragma unroll
  for (int j = 0; j < 16; ++j) tile[i][cc + j] = buf.u[j];
  __syncthreads();
#pragma unroll
  for (int j = 0; j < 16; ++j) buf.u[j] = tile[cc + j][i];
  uint4* o = (uint4*)(vT + ((size_t)(b * 4 + kv) * 128 + d0 + i) * S + s0 + cc);
  o[0] = buf.v[0]; o[1] = buf.v[1];
}

// ---------------------------------------------------------------------------
// MFMA flash attention v3, non-causal. Block = (b,h,128 q-rows), 4 waves x 32
// rows — the R8 (best-measured) geometry. Geometry lessons: R7 (K from L2):
// grid caps blocks/CU at 2, L2 latency on MFMA path — 2x loss. R9 (256 rows,
// 1 block/CU): halved FETCH but +5us — flash is NOT BW-bound; the 2nd
// independent block per CU absorbs drain stalls. Keep 2 blocks/CU.
__global__ __launch_bounds__(256, 2) void flash_attn(const unsigned short* __restrict__ qT,
                                                     const unsigned short* __restrict__ kT,
                                                     const unsigned short* __restrict__ vT,
                                                     unsigned short* __restrict__ ao) {
  const int S = 2048;
  int bid = blockIdx.x;
  int qt = bid & 15, h = (bid >> 4) & 15, b = bid >> 8;
  int kv = h >> 2;
  int tid = threadIdx.x;
  int lane = tid & 63, wave = tid >> 6;
  int l15 = lane & 15, quad = lane >> 4;

  __shared__ unsigned short Ks[2][64 * 128];   // keys x dh, 16 chunks/row, XOR swizzled
  __shared__ unsigned short VTs[2][128 * 64];  // d x keys, 8 chunks/row, XOR swizzled
  __shared__ unsigned short Ps[4][32 * 64];    // per-wave P in PV-A layout, swizzled
  unsigned short* Psw = Ps[wave];

  // Q fragments (B-operand of S^T: B[n=qrow][k=dh]), register-resident
  short8 bq[2][4];
  const unsigned short* qbase = qT + ((size_t)(b * 16 + h) * S + qt * 128 + wave * 32) * 128;
#pragma unroll
  for (int nt = 0; nt < 2; ++nt)
#pragma unroll
    for (int kk = 0; kk < 4; ++kk)
      bq[nt][kk] = *(const short8*)(qbase + (size_t)(nt * 16 + l15) * 128 + kk * 32 + quad * 8);

  floatx4 O[2][8];
#pragma unroll
  for (int mt = 0; mt < 2; ++mt)
#pragma unroll
    for (int dt = 0; dt < 8; ++dt) O[mt][dt] = (floatx4){0.f, 0.f, 0.f, 0.f};
  float l_acc[2] = {0.f, 0.f};

  const size_t kbase = (size_t)(b * 4 + kv) * S * 128;
  const size_t vbase = (size_t)(b * 4 + kv) * 128 * S;

  // prefetch tile 0 into buffer 0
#pragma unroll
  for (int i = 0; i < 4; ++i) {
    int Lc = (wave * 4 + i) * 64 + lane;
    int row = Lc >> 4, cjk = (lane & 15) ^ (row & 7);
    async16(Ks[0] + (size_t)Lc * 8, kT + kbase + (size_t)row * 128 + cjk * 8);
    int d = Lc >> 3, cjv = (lane & 7) ^ (d & 7);
    async16(VTs[0] + (size_t)Lc * 8, vT + vbase + (size_t)d * S + cjv * 8);
  }

  for (int kt = 0; kt < 32; ++kt) {
    int cur = kt & 1;
    __syncthreads();  // drains prefetch for tile kt; fences reads of buf cur^1 (kt-1)
    if (kt + 1 < 32) {
#pragma unroll
      for (int i = 0; i < 4; ++i) {
        int Lc = (wave * 4 + i) * 64 + lane;
        int row = Lc >> 4, cjk = (lane & 15) ^ (row & 7);
        async16(Ks[cur ^ 1] + (size_t)Lc * 8,
                kT + kbase + (size_t)((kt + 1) * 64 + row) * 128 + cjk * 8);
        int d = Lc >> 3, cjv = (lane & 7) ^ (d & 7);
        async16(VTs[cur ^ 1] + (size_t)Lc * 8,
                vT + vbase + (size_t)d * S + (kt + 1) * 64 + cjv * 8);
      }
    }

    // S^T = K * Q^T : C[m=key][n=qrow]
    floatx4 st[4][2];
#pragma unroll
    for (int a = 0; a < 4; ++a)
#pragma unroll
      for (int nt = 0; nt < 2; ++nt) st[a][nt] = (floatx4){0.f, 0.f, 0.f, 0.f};
    __builtin_amdgcn_s_setprio(1);
#pragma unroll
    for (int kk = 0; kk < 4; ++kk)
#pragma unroll
      for (int a = 0; a < 4; ++a) {
        int m = a * 16 + l15;
        short8 ak = *(const short8*)(&Ks[cur][(m * 16 + ((kk * 4 + quad) ^ (m & 7))) * 8]);
#pragma unroll
        for (int nt = 0; nt < 2; ++nt)
          st[a][nt] = __builtin_amdgcn_mfma_f32_16x16x32_bf16(ak, bq[nt][kk], st[a][nt], 0, 0, 0);
      }
    __builtin_amdgcn_s_setprio(0);

    // P = exp2(S^T); pack to bf16 into per-wave Ps (PV-A layout); l partials per lane.
#pragma unroll
    for (int nt = 0; nt < 2; ++nt) {
      int m = nt * 16 + l15;
#pragma unroll
      for (int a = 0; a < 4; ++a) {
        float e0 = __builtin_amdgcn_exp2f(st[a][nt][0]);
        float e1 = __builtin_amdgcn_exp2f(st[a][nt][1]);
        float e2 = __builtin_amdgcn_exp2f(st[a][nt][2]);
        float e3 = __builtin_amdgcn_exp2f(st[a][nt][3]);
        l_acc[nt] += (e0 + e1) + (e2 + e3);
        u32 p01 = __builtin_amdgcn_perm(fbits(e1) + 0x8000u, fbits(e0) + 0x8000u, 0x07060302u);
        u32 p23 = __builtin_amdgcn_perm(fbits(e3) + 0x8000u, fbits(e2) + 0x8000u, 0x07060302u);
        int c = (a * 2 + (quad >> 1)) ^ (m & 7);
        uint2 pk; pk.x = p01; pk.y = p23;
        *(uint2*)(&Psw[(m * 8 + c) * 8 + (quad & 1) * 4]) = pk;
      }
    }

    // PV: O[m=qrow][n=d] += P[m][key] * VT[n][key]
    __builtin_amdgcn_s_setprio(1);
#pragma unroll
    for (int kk2 = 0; kk2 < 2; ++kk2) {
      short8 ap[2];
#pragma unroll
      for (int mt = 0; mt < 2; ++mt) {
        int m = mt * 16 + l15;
        ap[mt] = *(const short8*)(&Psw[(m * 8 + ((kk2 * 4 + quad) ^ (m & 7))) * 8]);
      }
#pragma unroll
      for (int dt = 0; dt < 8; ++dt) {
        int n = dt * 16 + l15;
        short8 bv = *(const short8*)(&VTs[cur][(n * 8 + ((kk2 * 4 + quad) ^ (n & 7))) * 8]);
#pragma unroll
        for (int mt = 0; mt < 2; ++mt)
          O[mt][dt] = __builtin_amdgcn_mfma_f32_16x16x32_bf16(ap[mt], bv, O[mt][dt], 0, 0, 0);
      }
    }
    __builtin_amdgcn_s_setprio(0);
  }

  // epilogue: reduce l across quads, normalize, store
  float linv[2];
#pragma unroll
  for (int nt = 0; nt < 2; ++nt) {
    float l = l_acc[nt];
    l += __shfl_xor(l, 16, 64);
    l += __shfl_xor(l, 32, 64);
    linv[nt] = 1.f / l;
  }
#pragma unroll
  for (int mt = 0; mt < 2; ++mt)
#pragma unroll
    for (int r = 0; r < 4; ++r) {
      float inv = __shfl(linv[mt], quad * 4 + r, 64);
      int s = qt * 128 + wave * 32 + mt * 16 + quad * 4 + r;
#pragma unroll
      for (int dt = 0; dt < 8; ++dt) {
        int d = dt * 16 + l15;
        ao[((size_t)(b * S + s) * 16 + h) * 128 + d] = f2bf(O[mt][dt][r] * inv);
      }
    }
}

// ---------------------------------------------------------------------------
extern "C" void kernel_launch(void* const* d_in, const int* in_sizes, int n_in,
                              void* d_out, int out_size, void* d_ws, size_t ws_size,
                              hipStream_t stream) {
  const float* x  = (const float*)d_in[0];
  const float* Wq = (const float*)d_in[1];
  const float* Wk = (const float*)d_in[2];
  const float* Wv = (const float*)d_in[3];
  const float* Wo = (const float*)d_in[4];
  const float* qw = (const float*)d_in[5];
  const float* kw = (const float*)d_in[6];
  float* out = (float*)d_out;

  unsigned short* p = (unsigned short*)d_ws;
  unsigned short* xbf   = p; p += (size_t)4096 * 2048;
  unsigned short* WTqkv = p; p += (size_t)3072 * 2048;
  unsigned short* WoT   = p; p += (size_t)2048 * 2048;
  unsigned short* qkv   = p; p += (size_t)4096 * 3072;
  unsigned short* qTb   = p; p += (size_t)2 * 16 * 2048 * 128;
  unsigned short* kTb   = p; p += (size_t)2 * 4 * 2048 * 128;
  unsigned short* vTb   = p; p += (size_t)2 * 4 * 2048 * 128;
  unsigned short* ao    = p; p += (size_t)4096 * 2048;
  float2* rope_tab = (float2*)p; p += (size_t)2048 * 64 * 4;  // 1MB table

  // fused preprocessing: x-convert || weight transposes || RoPE table (512 blk)
  prep1<<<7168, 256, 0, stream>>>(x, Wq, Wk, Wv, Wo, xbf, WTqkv, WoT, rope_tab);

  // qkv projection: 8-phase 256x192 -> 16 x 16 = 256 blocks = 1 per CU
  gemm_nt_256x192<<<256, 512, 0, stream>>>(xbf, WTqkv, qkv, 4096, 3072, 2048);

  // fused: norm+rope (table-driven) || v-transpose
  prep2<<<2560, 256, 0, stream>>>(qkv, qw, kw, rope_tab, qTb, kTb, vTb);

  // flash: R8 geometry (128 q-rows, 4 waves, 2 blocks/CU)
  flash_attn<<<512, 256, 0, stream>>>(qTb, kTb, vTb, ao);

  // output projection: 8-phase 128x256 -> 32 x 8 = 256 blocks = 1 per CU
  gemm_nt_128x256<<<256, 512, 0, stream>>>(ao, WoT, out, 4096, 2048, 2048);
}

// Round 12
// 301.197 us; speedup vs baseline: 1.0550x; 1.0205x over previous
//
#include <hip/hip_runtime.h>
#include <stdint.h>

#define LOG2E 1.4426950408889634f

typedef __attribute__((ext_vector_type(8))) short short8;
typedef __attribute__((ext_vector_type(4))) float floatx4;
typedef unsigned int u32;

__device__ __forceinline__ float bf2f(unsigned short h) {
  union { unsigned int u; float f; } v; v.u = ((unsigned int)h) << 16; return v.f;
}
__device__ __forceinline__ unsigned short f2bf(float f) {
  union { float f; unsigned int u; } v; v.f = f;
  unsigned int r = v.u + 0x7FFFu + ((v.u >> 16) & 1u);
  return (unsigned short)(r >> 16);
}
__device__ __forceinline__ u32 fbits(float f) {
  union { float f; u32 u; } v; v.f = f; return v.u;
}
// async global->LDS, 16B per lane. dst must be wave-contiguous (base + lane*16).
__device__ __forceinline__ void async16(void* lds, const void* g) {
  __builtin_amdgcn_global_load_lds((const __attribute__((address_space(1))) u32*)g,
                                   (__attribute__((address_space(3))) u32*)lds, 16, 0, 0);
}

// ---------------------------------------------------------------------------
// prep1: fp32->bf16 x-convert, all 4 weight transposes, AND RoPE cos/sin
// table fill in ONE launch. Blocks [0,4096): x cvt; [4096,6656): W transpose;
// [6656,7168): rope table — 512 blocks x 4 s-rows = 2048 rows x 64 j float2.
__global__ __launch_bounds__(256) void prep1(const float* __restrict__ x,
                                             const float* __restrict__ Wq,
                                             const float* __restrict__ Wk,
                                             const float* __restrict__ Wv,
                                             const float* __restrict__ Wo,
                                             unsigned short* __restrict__ xbf,
                                             unsigned short* __restrict__ WTqkv,
                                             unsigned short* __restrict__ WoT,
                                             float2* __restrict__ rope_tab) {
  __shared__ unsigned short tile[64][65];
  int bid = blockIdx.x;
  if (bid < 4096) {
    int i = (bid * 256 + threadIdx.x) * 8;
    float4 a = ((const float4*)(x + i))[0];
    float4 b = ((const float4*)(x + i))[1];
    union { uint4 v; unsigned short u[8]; } o;
    o.u[0] = f2bf(a.x); o.u[1] = f2bf(a.y); o.u[2] = f2bf(a.z); o.u[3] = f2bf(a.w);
    o.u[4] = f2bf(b.x); o.u[5] = f2bf(b.y); o.u[6] = f2bf(b.z); o.u[7] = f2bf(b.w);
    *(uint4*)(xbf + i) = o.v;
    return;
  }
  if (bid >= 6656) {
    int t = (bid - 6656) * 4 + (threadIdx.x >> 6);
    int j = threadIdx.x & 63;
    float ang = (float)t * exp2f((float)j * -0.2076205059304601f);
    rope_tab[(t << 6) + j] = make_float2(cosf(ang), sinf(ang));
    return;
  }
  bid -= 4096;
  const int R = 2048;
  const float* src; unsigned short* dst; int C;
  if (bid < 1024) { src = Wq; dst = WTqkv; C = 2048; }
  else if (bid < 1280) { src = Wk; dst = WTqkv + (size_t)2048 * 2048; C = 512; bid -= 1024; }
  else if (bid < 1536) { src = Wv; dst = WTqkv + (size_t)2048 * 2048 + (size_t)512 * 2048; C = 512; bid -= 1280; }
  else { src = Wo; dst = WoT; C = 2048; bid -= 1536; }

  int tc = C >> 6;
  int br = bid / tc, bc = bid % tc;
  int r0 = br << 6, c0 = bc << 6;
  int i = threadIdx.x >> 2, cc = (threadIdx.x & 3) << 4;
  const float4* g = (const float4*)(src + (size_t)(r0 + i) * C + c0 + cc);
  float4 f0 = g[0], f1 = g[1], f2 = g[2], f3 = g[3];
  unsigned short u[16];
  u[0]=f2bf(f0.x); u[1]=f2bf(f0.y); u[2]=f2bf(f0.z); u[3]=f2bf(f0.w);
  u[4]=f2bf(f1.x); u[5]=f2bf(f1.y); u[6]=f2bf(f1.z); u[7]=f2bf(f1.w);
  u[8]=f2bf(f2.x); u[9]=f2bf(f2.y); u[10]=f2bf(f2.z); u[11]=f2bf(f2.w);
  u[12]=f2bf(f3.x); u[13]=f2bf(f3.y); u[14]=f2bf(f3.z); u[15]=f2bf(f3.w);
#pragma unroll
  for (int j = 0; j < 16; ++j) tile[i][cc + j] = u[j];
  __syncthreads();
  union { uint4 v[2]; unsigned short u[16]; } buf;
#pragma unroll
  for (int j = 0; j < 16; ++j) buf.u[j] = tile[cc + j][i];
  uint4* o = (uint4*)(dst + (size_t)(c0 + i) * R + r0 + cc);
  o[0] = buf.v[0]; o[1] = buf.v[1];
}

// ---------------------------------------------------------------------------
// 8-phase 256x192 NT GEMM, bf16 out — qkv projection. 256 blocks = 1/CU (R6).
// R12: re-waved 4M x 2N (per-wave 64x96, acc[4][6]) -> UNIFORM 12 MFMA per
// phase (was 16/16/8/8; the 8-MFMA phases under-filled their barrier window).
// Reads/tile 20 (was 22). Staging identical. Deadness: A(t) reads done ph2
// (a0@ph1, a1@ph2) -> in-place A restage ph3/ph4; B(t) reads done ph3 (b0@ph1,
// b1@ph3); B(t+1) staged ph1 to opposite buffer. vmcnt(4)@ph4: FIFO
// [A(t+1)4, B(t+1)3, A(t+2)h0 2, A(t+2)h1 2] -> drain-to-4 retires t+1. 
__global__ __launch_bounds__(512, 2) void gemm_nt_256x192(const unsigned short* __restrict__ A,
                                                          const unsigned short* __restrict__ BT,
                                                          unsigned short* __restrict__ C,
                                                          int M, int N, int K) {
  (void)M;
  __shared__ unsigned short As[2][256 * 64];
  __shared__ unsigned short Bs[2][192 * 64];
  const int nbn = N / 192;
  const int nwg = gridDim.x;
  int wg = blockIdx.x;
  {  // XCD-aware swizzle (bijective: nwg % 8 == 0)
    int cpx = nwg >> 3;
    wg = (wg & 7) * cpx + (wg >> 3);
  }
  const int m0 = (wg / nbn) << 8;
  const int n0 = (wg % nbn) * 192;
  const int tid = threadIdx.x;
  const int lane = tid & 63, wave = tid >> 6;
  const int l15 = lane & 15, quad = lane >> 4;
  const int wr = wave >> 1, wc = wave & 1;   // 4 x 2 wave grid
  const int rA = wr * 64 + l15;              // + mf*16, mf in [0,4)
  const int rB = wc * 96 + l15;              // + nf*16, nf in [0,6)

  floatx4 acc[4][6];
#pragma unroll
  for (int i = 0; i < 4; ++i)
#pragma unroll
    for (int j = 0; j < 6; ++j) acc[i][j] = (floatx4){0.f, 0.f, 0.f, 0.f};

  const unsigned short* Ag = A + (size_t)m0 * K;
  const unsigned short* Bg = BT + (size_t)n0 * K;

  // A row-half h (128 rows x 64k = 16KB): 2 loads/thread.
  auto STAGE_A = [&](unsigned short* dst, const unsigned short* g, int h) {
#pragma unroll
    for (int j = 0; j < 2; ++j) {
      int idx = j * 512 + tid;              // [0,1024)
      int row = h * 128 + (idx >> 3);
      int cl = (idx & 7) ^ (row & 7);
      async16(dst + (size_t)h * 8192 + (size_t)idx * 8, g + (size_t)row * K + cl * 8);
    }
  };
  // B full tile (192 rows x 64k = 24KB): 3 loads/thread.
  auto STAGE_B = [&](unsigned short* dst, const unsigned short* g) {
#pragma unroll
    for (int j = 0; j < 3; ++j) {
      int idx = j * 512 + tid;              // [0,1536)
      int row = idx >> 3;
      int cl = (idx & 7) ^ (row & 7);
      async16(dst + (size_t)idx * 8, g + (size_t)row * K + cl * 8);
    }
  };
  auto RD = [&](const unsigned short* buf, int row, int ks) -> short8 {
    int sc = ((ks << 2) + quad) ^ (row & 7);
    return *(const short8*)(buf + row * 64 + sc * 8);
  };

#define BAR() __builtin_amdgcn_s_barrier()
#define WAITL0() asm volatile("s_waitcnt lgkmcnt(0)" ::: "memory")

  // prologue: A(0) h0,h1 [4]; B(0) [3]; A(1) h0,h1 [4] = 11 loads/thread
  STAGE_A(As[0], Ag, 0); STAGE_A(As[0], Ag, 1);
  STAGE_B(Bs[0], Bg);
  STAGE_A(As[1], Ag + 64, 0); STAGE_A(As[1], Ag + 64, 1);
  asm volatile("s_waitcnt vmcnt(4)" ::: "memory");   // tile0 landed; A(1) in flight
  BAR();

  const int NT = K >> 6;
  short8 a0[2][2], a1[2][2], b0[3][2], b1[3][2];
  for (int t = 0; t < NT; ++t) {
    const unsigned short* Ac = As[t & 1];
    const unsigned short* Bc = Bs[t & 1];
    unsigned short* Ast = As[t & 1];         // stage target: A(t+2), in-place
    unsigned short* Bst = Bs[(t + 1) & 1];   // stage target: B(t+1)

    // ---- phase 1: read a0 (mf0-1) [4] + b0 (nf0-2) [6]; stage B(t+1) [3]
#pragma unroll
    for (int mf = 0; mf < 2; ++mf)
#pragma unroll
      for (int ks = 0; ks < 2; ++ks) a0[mf][ks] = RD(Ac, rA + mf * 16, ks);
#pragma unroll
    for (int nf = 0; nf < 3; ++nf)
#pragma unroll
      for (int ks = 0; ks < 2; ++ks) b0[nf][ks] = RD(Bc, rB + nf * 16, ks);
    if (t + 1 < NT) STAGE_B(Bst, Bg + (size_t)(t + 1) * 64);
    asm volatile("s_waitcnt lgkmcnt(8)" ::: "memory");
    BAR(); WAITL0();
    __builtin_amdgcn_s_setprio(1);
#pragma unroll
    for (int mf = 0; mf < 2; ++mf)
#pragma unroll
      for (int nf = 0; nf < 3; ++nf)
#pragma unroll
        for (int ks = 0; ks < 2; ++ks)
          acc[mf][nf] = __builtin_amdgcn_mfma_f32_16x16x32_bf16(a0[mf][ks], b0[nf][ks], acc[mf][nf], 0, 0, 0);
    __builtin_amdgcn_s_setprio(0);
    BAR();

    // ---- phase 2: read a1 (mf2-3) [4]
#pragma unroll
    for (int mf = 0; mf < 2; ++mf)
#pragma unroll
      for (int ks = 0; ks < 2; ++ks) a1[mf][ks] = RD(Ac, rA + 32 + mf * 16, ks);
    BAR(); WAITL0();
    __builtin_amdgcn_s_setprio(1);
#pragma unroll
    for (int mf = 0; mf < 2; ++mf)
#pragma unroll
      for (int nf = 0; nf < 3; ++nf)
#pragma unroll
        for (int ks = 0; ks < 2; ++ks)
          acc[2 + mf][nf] = __builtin_amdgcn_mfma_f32_16x16x32_bf16(a1[mf][ks], b0[nf][ks], acc[2 + mf][nf], 0, 0, 0);
    __builtin_amdgcn_s_setprio(0);
    BAR();

    // ---- phase 3: read b1 (nf3-5) [6]; stage A(t+2)h0 (A(t) dead after ph2)
#pragma unroll
    for (int nf = 0; nf < 3; ++nf)
#pragma unroll
      for (int ks = 0; ks < 2; ++ks) b1[nf][ks] = RD(Bc, rB + 48 + nf * 16, ks);
    if (t + 2 < NT) STAGE_A(Ast, Ag + (size_t)(t + 2) * 64, 0);
    BAR(); WAITL0();
    __builtin_amdgcn_s_setprio(1);
#pragma unroll
    for (int mf = 0; mf < 2; ++mf)
#pragma unroll
      for (int nf = 0; nf < 3; ++nf)
#pragma unroll
        for (int ks = 0; ks < 2; ++ks)
          acc[2 + mf][3 + nf] = __builtin_amdgcn_mfma_f32_16x16x32_bf16(a1[mf][ks], b1[nf][ks], acc[2 + mf][3 + nf], 0, 0, 0);
    __builtin_amdgcn_s_setprio(0);
    BAR();

    // ---- phase 4: stage A(t+2)h1; counted vmcnt(4) per tile
    if (t + 2 < NT) {
      STAGE_A(Ast, Ag + (size_t)(t + 2) * 64, 1);
      asm volatile("s_waitcnt vmcnt(4)" ::: "memory");  // tile t+1 fully landed
    } else {
      asm volatile("s_waitcnt vmcnt(0)" ::: "memory");  // tail drain
    }
    BAR();
    __builtin_amdgcn_s_setprio(1);
#pragma unroll
    for (int mf = 0; mf < 2; ++mf)
#pragma unroll
      for (int nf = 0; nf < 3; ++nf)
#pragma unroll
        for (int ks = 0; ks < 2; ++ks)
          acc[mf][3 + nf] = __builtin_amdgcn_mfma_f32_16x16x32_bf16(a0[mf][ks], b1[nf][ks], acc[mf][3 + nf], 0, 0, 0);
    __builtin_amdgcn_s_setprio(0);
    BAR();
  }
#undef BAR
#undef WAITL0

#pragma unroll
  for (int mf = 0; mf < 4; ++mf)
#pragma unroll
    for (int nf = 0; nf < 6; ++nf)
#pragma unroll
      for (int r = 0; r < 4; ++r) {
        int m = m0 + wr * 64 + mf * 16 + quad * 4 + r;
        int n = n0 + wc * 96 + nf * 16 + l15;
        C[(size_t)m * N + n] = f2bf(acc[mf][nf][r]);
      }
}

// ---------------------------------------------------------------------------
// 8-phase 128x256 NT GEMM (fp32 out). R4: grid 256 = 1 block/CU.
__global__ __launch_bounds__(512, 2) void gemm_nt_128x256(const unsigned short* __restrict__ A,
                                                          const unsigned short* __restrict__ BT,
                                                          float* __restrict__ C,
                                                          int M, int N, int K) {
  (void)M;
  __shared__ unsigned short As[2][128 * 64];
  __shared__ unsigned short Bs[2][256 * 64];
  const int nbn = N >> 8;
  const int nwg = gridDim.x;
  int wg = blockIdx.x;
  {  // XCD-aware swizzle (bijective: nwg % 8 == 0)
    int cpx = nwg >> 3;
    wg = (wg & 7) * cpx + (wg >> 3);
  }
  const int m0 = (wg / nbn) << 7;
  const int n0 = (wg % nbn) << 8;
  const int tid = threadIdx.x;
  const int lane = tid & 63, wave = tid >> 6;
  const int l15 = lane & 15, quad = lane >> 4;
  const int wr = wave >> 2, wc = wave & 3;   // 2 x 4 wave grid
  const int rA = wr * 64 + l15;              // + mf*16, mf in [0,4)
  const int rB = wc * 64 + l15;              // + nf*16, nf in [0,4)

  floatx4 acc[4][4];
#pragma unroll
  for (int i = 0; i < 4; ++i)
#pragma unroll
    for (int j = 0; j < 4; ++j) acc[i][j] = (floatx4){0.f, 0.f, 0.f, 0.f};

  const unsigned short* Ag = A + (size_t)m0 * K;
  const unsigned short* Bg = BT + (size_t)n0 * K;

  // B-half: 128 rows x 64k (16KB), 2 loads/thread.
  auto STAGE_B = [&](unsigned short* dst, const unsigned short* g, int h) {
#pragma unroll
    for (int j = 0; j < 2; ++j) {
      int idx = j * 512 + tid;
      int row = h * 128 + (idx >> 3);
      int cl = (idx & 7) ^ (row & 7);
      async16(dst + (size_t)h * 8192 + (size_t)idx * 8, g + (size_t)row * K + cl * 8);
    }
  };
  // A-half: 64 rows x 64k (8KB), 1 load/thread.
  auto STAGE_A = [&](unsigned short* dst, const unsigned short* g, int h) {
    int idx = tid;
    int row = h * 64 + (idx >> 3);
    int cl = (idx & 7) ^ (row & 7);
    async16(dst + (size_t)h * 4096 + (size_t)idx * 8, g + (size_t)row * K + cl * 8);
  };
  auto RD = [&](const unsigned short* buf, int row, int ks) -> short8 {
    int sc = ((ks << 2) + quad) ^ (row & 7);
    return *(const short8*)(buf + row * 64 + sc * 8);
  };

#define BAR() __builtin_amdgcn_s_barrier()
#define WAITL0() asm volatile("s_waitcnt lgkmcnt(0)" ::: "memory")

  // prologue: A(0) h0,h1 [2]; B(0) h0,h1 [4]; A(1) h0,h1 [2] = 8 loads/thread
  STAGE_A(As[0], Ag, 0); STAGE_A(As[0], Ag, 1);
  STAGE_B(Bs[0], Bg, 0); STAGE_B(Bs[0], Bg, 1);
  STAGE_A(As[1], Ag + 64, 0); STAGE_A(As[1], Ag + 64, 1);
  asm volatile("s_waitcnt vmcnt(2)" ::: "memory");   // tile0 landed; A(1) in flight
  BAR();

  const int NT = K >> 6;
  short8 a0[2][2], a1[2][2], b0[2][2], b1[2][2];
  for (int t = 0; t < NT; ++t) {
    const unsigned short* Ac = As[t & 1];
    const unsigned short* Bc = Bs[t & 1];
    unsigned short* Ast = As[t & 1];         // stage target: A(t+2), in-place
    unsigned short* Bst = Bs[(t + 1) & 1];   // stage target: B(t+1)

    // ---- phase 1: read a0 (mf0-1) + b0 (nf0-1) [8]; stage B(t+1)h0
#pragma unroll
    for (int mf = 0; mf < 2; ++mf)
#pragma unroll
      for (int ks = 0; ks < 2; ++ks) a0[mf][ks] = RD(Ac, rA + mf * 16, ks);
#pragma unroll
    for (int nf = 0; nf < 2; ++nf)
#pragma unroll
      for (int ks = 0; ks < 2; ++ks) b0[nf][ks] = RD(Bc, rB + nf * 16, ks);
    if (t + 1 < NT) STAGE_B(Bst, Bg + (size_t)(t + 1) * 64, 0);
    asm volatile("s_waitcnt lgkmcnt(4)" ::: "memory");
    BAR(); WAITL0();
    __builtin_amdgcn_s_setprio(1);
#pragma unroll
    for (int mf = 0; mf < 2; ++mf)
#pragma unroll
      for (int nf = 0; nf < 2; ++nf)
#pragma unroll
        for (int ks = 0; ks < 2; ++ks)
          acc[mf][nf] = __builtin_amdgcn_mfma_f32_16x16x32_bf16(a0[mf][ks], b0[nf][ks], acc[mf][nf], 0, 0, 0);
    __builtin_amdgcn_s_setprio(0);
    BAR();

    // ---- phase 2: read a1 (mf2-3) [4]; stage B(t+1)h1
#pragma unroll
    for (int mf = 0; mf < 2; ++mf)
#pragma unroll
      for (int ks = 0; ks < 2; ++ks) a1[mf][ks] = RD(Ac, rA + 32 + mf * 16, ks);
    if (t + 1 < NT) STAGE_B(Bst, Bg + (size_t)(t + 1) * 64, 1);
    BAR(); WAITL0();
    __builtin_amdgcn_s_setprio(1);
#pragma unroll
    for (int mf = 0; mf < 2; ++mf)
#pragma unroll
      for (int nf = 0; nf < 2; ++nf)
#pragma unroll
        for (int ks = 0; ks < 2; ++ks)
          acc[2 + mf][nf] = __builtin_amdgcn_mfma_f32_16x16x32_bf16(a1[mf][ks], b0[nf][ks], acc[2 + mf][nf], 0, 0, 0);
    __builtin_amdgcn_s_setprio(0);
    BAR();

    // ---- phase 3: read b1 (nf2-3) [4]; stage A(t+2)h0 (A(t) dead after ph2)
#pragma unroll
    for (int nf = 0; nf < 2; ++nf)
#pragma unroll
      for (int ks = 0; ks < 2; ++ks) b1[nf][ks] = RD(Bc, rB + 32 + nf * 16, ks);
    if (t + 2 < NT) STAGE_A(Ast, Ag + (size_t)(t + 2) * 64, 0);
    BAR(); WAITL0();
    __builtin_amdgcn_s_setprio(1);
#pragma unroll
    for (int mf = 0; mf < 2; ++mf)
#pragma unroll
      for (int nf = 0; nf < 2; ++nf)
#pragma unroll
        for (int ks = 0; ks < 2; ++ks)
          acc[2 + mf][2 + nf] = __builtin_amdgcn_mfma_f32_16x16x32_bf16(a1[mf][ks], b1[nf][ks], acc[2 + mf][2 + nf], 0, 0, 0);
    __builtin_amdgcn_s_setprio(0);
    BAR();

    // ---- phase 4: no reads; stage A(t+2)h1; counted vmcnt(2) per tile
    if (t + 2 < NT) {
      STAGE_A(Ast, Ag + (size_t)(t + 2) * 64, 1);
      asm volatile("s_waitcnt vmcnt(2)" ::: "memory");  // tile t+1 fully landed
    } else {
      asm volatile("s_waitcnt vmcnt(0)" ::: "memory");  // tail drain
    }
    BAR();
    __builtin_amdgcn_s_setprio(1);
#pragma unroll
    for (int mf = 0; mf < 2; ++mf)
#pragma unroll
      for (int nf = 0; nf < 2; ++nf)
#pragma unroll
        for (int ks = 0; ks < 2; ++ks)
          acc[mf][2 + nf] = __builtin_amdgcn_mfma_f32_16x16x32_bf16(a0[mf][ks], b1[nf][ks], acc[mf][2 + nf], 0, 0, 0);
    __builtin_amdgcn_s_setprio(0);
    BAR();
  }
#undef BAR
#undef WAITL0

#pragma unroll
  for (int mf = 0; mf < 4; ++mf)
#pragma unroll
    for (int nf = 0; nf < 4; ++nf)
#pragma unroll
      for (int r = 0; r < 4; ++r) {
        int m = m0 + wr * 64 + mf * 16 + quad * 4 + r;
        int n = n0 + wc * 64 + nf * 16 + l15;
        C[(size_t)m * N + n] = acc[mf][nf][r];
      }
}

// ---------------------------------------------------------------------------
// prep2: RMS-norm+RoPE AND V-transpose in ONE launch. cos/sin from the
// prep1-filled table (one coalesced 8B load/lane/slot).
__global__ __launch_bounds__(256) void prep2(const unsigned short* __restrict__ qkv,
                                             const float* __restrict__ qw,
                                             const float* __restrict__ kw,
                                             const float2* __restrict__ rope_tab,
                                             unsigned short* __restrict__ qT,
                                             unsigned short* __restrict__ kT,
                                             unsigned short* __restrict__ vT) {
  const int S = 2048;
  __shared__ unsigned short tile[64][65];
  int bid = blockIdx.x;
  if (bid < 2048) {
    int wave = threadIdx.x >> 6, lane = threadIdx.x & 63;
    int wid0 = bid * 4 + wave;                   // [0,8192)
    const float qwl1 = qw[lane], qwl2 = qw[lane + 64];
    const float kwl1 = kw[lane], kwl2 = kw[lane + 64];
    for (int k = 0; k < 10; ++k) {
      int wid = wid0 + k * 8192;                 // [0,81920)
      int slot = wid % 20;
      int bs = wid / 20;
      int s = bs & (S - 1), b = bs >> 11;
      const unsigned short* src;
      unsigned short* dst;
      float w1, w2, scale;
      if (slot < 16) {
        src = qkv + (size_t)bs * 3072 + slot * 128;
        dst = qT + ((size_t)(b * 16 + slot) * S + s) * 128;
        w1 = qwl1; w2 = qwl2;
        scale = 0.08838834764831845f * 1.4426950408889634f;  // 1/sqrt(128)*log2(e)
      } else {
        int kvi = slot - 16;
        src = qkv + (size_t)bs * 3072 + 2048 + kvi * 128;
        dst = kT + ((size_t)(b * 4 + kvi) * S + s) * 128;
        w1 = kwl1; w2 = kwl2;
        scale = 1.0f;
      }
      float x1 = bf2f(src[lane]), x2 = bf2f(src[lane + 64]);
      float ss = x1 * x1 + x2 * x2;
#pragma unroll
      for (int m = 1; m < 64; m <<= 1) ss += __shfl_xor(ss, m, 64);
      float rms = rsqrtf(ss * (1.0f / 128.0f) + 1e-6f);
      float y1 = x1 * rms * w1;
      float y2 = x2 * rms * w2;
      float2 cs = rope_tab[(s << 6) + lane];
      float c = cs.x, sn = cs.y;
      float o1 = (y1 * c - y2 * sn) * scale;
      float o2 = (y2 * c + y1 * sn) * scale;
      dst[lane] = f2bf(o1);
      dst[lane + 64] = f2bf(o2);
    }
    return;
  }
  bid -= 2048;
  // ---- V transpose: (B,S,KV,128) -> (B,KV,128,S)
  int dt = bid & 1, st = (bid >> 1) & 31, kv = (bid >> 6) & 3, b = bid >> 8;
  int s0 = st << 6, d0 = dt << 6;
  int i = threadIdx.x >> 2, cc = (threadIdx.x & 3) << 4;
  union { uint4 v[2]; unsigned short u[16]; } buf;
  const uint4* g = (const uint4*)(qkv + ((size_t)(b * S) + s0 + i) * 3072 + 2560 + kv * 128 + d0 + cc);
  buf.v[0] = g[0]; buf.v[1] = g[1];
#pragma unroll
  for (int j = 0; j < 16; ++j) tile[i][cc + j] = buf.u[j];
  __syncthreads();
#pragma unroll
  for (int j = 0; j < 16; ++j) buf.u[j] = tile[cc + j][i];
  uint4* o = (uint4*)(vT + ((size_t)(b * 4 + kv) * 128 + d0 + i) * S + s0 + cc);
  o[0] = buf.v[0]; o[1] = buf.v[1];
}

// ---------------------------------------------------------------------------
// MFMA flash attention v3, non-causal. Block = (b,h,128 q-rows), 4 waves x 32
// rows (R8 best-measured geometry). R12: P-pack and PV interleaved by key-half
// — pack keys 0-31 (a=0,1), PV kk2=0, pack keys 32-63 (a=2,3), PV kk2=1.
// Halves the serial VALU chain before the first PV MFMA; Ps deps are
// wave-local so this is a pure reorder (no sync change).
__global__ __launch_bounds__(256, 2) void flash_attn(const unsigned short* __restrict__ qT,
                                                     const unsigned short* __restrict__ kT,
                                                     const unsigned short* __restrict__ vT,
                                                     unsigned short* __restrict__ ao) {
  const int S = 2048;
  int bid = blockIdx.x;
  int qt = bid & 15, h = (bid >> 4) & 15, b = bid >> 8;
  int kv = h >> 2;
  int tid = threadIdx.x;
  int lane = tid & 63, wave = tid >> 6;
  int l15 = lane & 15, quad = lane >> 4;

  __shared__ unsigned short Ks[2][64 * 128];   // keys x dh, 16 chunks/row, XOR swizzled
  __shared__ unsigned short VTs[2][128 * 64];  // d x keys, 8 chunks/row, XOR swizzled
  __shared__ unsigned short Ps[4][32 * 64];    // per-wave P in PV-A layout, swizzled
  unsigned short* Psw = Ps[wave];

  // Q fragments (B-operand of S^T: B[n=qrow][k=dh]), register-resident
  short8 bq[2][4];
  const unsigned short* qbase = qT + ((size_t)(b * 16 + h) * S + qt * 128 + wave * 32) * 128;
#pragma unroll
  for (int nt = 0; nt < 2; ++nt)
#pragma unroll
    for (int kk = 0; kk < 4; ++kk)
      bq[nt][kk] = *(const short8*)(qbase + (size_t)(nt * 16 + l15) * 128 + kk * 32 + quad * 8);

  floatx4 O[2][8];
#pragma unroll
  for (int mt = 0; mt < 2; ++mt)
#pragma unroll
    for (int dt = 0; dt < 8; ++dt) O[mt][dt] = (floatx4){0.f, 0.f, 0.f, 0.f};
  float l_acc[2] = {0.f, 0.f};

  const size_t kbase = (size_t)(b * 4 + kv) * S * 128;
  const size_t vbase = (size_t)(b * 4 + kv) * 128 * S;

  // prefetch tile 0 into buffer 0
#pragma unroll
  for (int i = 0; i < 4; ++i) {
    int Lc = (wave * 4 + i) * 64 + lane;
    int row = Lc >> 4, cjk = (lane & 15) ^ (row & 7);
    async16(Ks[0] + (size_t)Lc * 8, kT + kbase + (size_t)row * 128 + cjk * 8);
    int d = Lc >> 3, cjv = (lane & 7) ^ (d & 7);
    async16(VTs[0] + (size_t)Lc * 8, vT + vbase + (size_t)d * S + cjv * 8);
  }

  for (int kt = 0; kt < 32; ++kt) {
    int cur = kt & 1;
    __syncthreads();  // drains prefetch for tile kt; fences reads of buf cur^1 (kt-1)
    if (kt + 1 < 32) {
#pragma unroll
      for (int i = 0; i < 4; ++i) {
        int Lc = (wave * 4 + i) * 64 + lane;
        int row = Lc >> 4, cjk = (lane & 15) ^ (row & 7);
        async16(Ks[cur ^ 1] + (size_t)Lc * 8,
                kT + kbase + (size_t)((kt + 1) * 64 + row) * 128 + cjk * 8);
        int d = Lc >> 3, cjv = (lane & 7) ^ (d & 7);
        async16(VTs[cur ^ 1] + (size_t)Lc * 8,
                vT + vbase + (size_t)d * S + (kt + 1) * 64 + cjv * 8);
      }
    }

    // S^T = K * Q^T : C[m=key][n=qrow]
    floatx4 st[4][2];
#pragma unroll
    for (int a = 0; a < 4; ++a)
#pragma unroll
      for (int nt = 0; nt < 2; ++nt) st[a][nt] = (floatx4){0.f, 0.f, 0.f, 0.f};
    __builtin_amdgcn_s_setprio(1);
#pragma unroll
    for (int kk = 0; kk < 4; ++kk)
#pragma unroll
      for (int a = 0; a < 4; ++a) {
        int m = a * 16 + l15;
        short8 ak = *(const short8*)(&Ks[cur][(m * 16 + ((kk * 4 + quad) ^ (m & 7))) * 8]);
#pragma unroll
        for (int nt = 0; nt < 2; ++nt)
          st[a][nt] = __builtin_amdgcn_mfma_f32_16x16x32_bf16(ak, bq[nt][kk], st[a][nt], 0, 0, 0);
      }
    __builtin_amdgcn_s_setprio(0);

    // Interleaved softmax-pack + PV by key-half (half=0: keys 0-31/kk2=0,
    // half=1: keys 32-63/kk2=1). Wave-local reorder only.
#pragma unroll
    for (int half = 0; half < 2; ++half) {
      // pack P for this half: a = half*2 + {0,1}
#pragma unroll
      for (int nt = 0; nt < 2; ++nt) {
        int m = nt * 16 + l15;
#pragma unroll
        for (int aa = 0; aa < 2; ++aa) {
          int a = half * 2 + aa;
          float e0 = __builtin_amdgcn_exp2f(st[a][nt][0]);
          float e1 = __builtin_amdgcn_exp2f(st[a][nt][1]);
          float e2 = __builtin_amdgcn_exp2f(st[a][nt][2]);
          float e3 = __builtin_amdgcn_exp2f(st[a][nt][3]);
          l_acc[nt] += (e0 + e1) + (e2 + e3);
          u32 p01 = __builtin_amdgcn_perm(fbits(e1) + 0x8000u, fbits(e0) + 0x8000u, 0x07060302u);
          u32 p23 = __builtin_amdgcn_perm(fbits(e3) + 0x8000u, fbits(e2) + 0x8000u, 0x07060302u);
          int c = (a * 2 + (quad >> 1)) ^ (m & 7);
          uint2 pk; pk.x = p01; pk.y = p23;
          *(uint2*)(&Psw[(m * 8 + c) * 8 + (quad & 1) * 4]) = pk;
        }
      }
      // PV for this half: kk2 = half
      {
        int kk2 = half;
        short8 ap[2];
#pragma unroll
        for (int mt = 0; mt < 2; ++mt) {
          int m = mt * 16 + l15;
          ap[mt] = *(const short8*)(&Psw[(m * 8 + ((kk2 * 4 + quad) ^ (m & 7))) * 8]);
        }
        __builtin_amdgcn_s_setprio(1);
#pragma unroll
        for (int dt = 0; dt < 8; ++dt) {
          int n = dt * 16 + l15;
          short8 bv = *(const short8*)(&VTs[cur][(n * 8 + ((kk2 * 4 + quad) ^ (n & 7))) * 8]);
#pragma unroll
          for (int mt = 0; mt < 2; ++mt)
            O[mt][dt] = __builtin_amdgcn_mfma_f32_16x16x32_bf16(ap[mt], bv, O[mt][dt], 0, 0, 0);
        }
        __builtin_amdgcn_s_setprio(0);
      }
    }
  }

  // epilogue: reduce l across quads, normalize, store
  float linv[2];
#pragma unroll
  for (int nt = 0; nt < 2; ++nt) {
    float l = l_acc[nt];
    l += __shfl_xor(l, 16, 64);
    l += __shfl_xor(l, 32, 64);
    linv[nt] = 1.f / l;
  }
#pragma unroll
  for (int mt = 0; mt < 2; ++mt)
#pragma unroll
    for (int r = 0; r < 4; ++r) {
      float inv = __shfl(linv[mt], quad * 4 + r, 64);
      int s = qt * 128 + wave * 32 + mt * 16 + quad * 4 + r;
#pragma unroll
      for (int dt = 0; dt < 8; ++dt) {
        int d = dt * 16 + l15;
        ao[((size_t)(b * S + s) * 16 + h) * 128 + d] = f2bf(O[mt][dt][r] * inv);
      }
    }
}

// ---------------------------------------------------------------------------
extern "C" void kernel_launch(void* const* d_in, const int* in_sizes, int n_in,
                              void* d_out, int out_size, void* d_ws, size_t ws_size,
                              hipStream_t stream) {
  const float* x  = (const float*)d_in[0];
  const float* Wq = (const float*)d_in[1];
  const float* Wk = (const float*)d_in[2];
  const float* Wv = (const float*)d_in[3];
  const float* Wo = (const float*)d_in[4];
  const float* qw = (const float*)d_in[5];
  const float* kw = (const float*)d_in[6];
  float* out = (float*)d_out;

  unsigned short* p = (unsigned short*)d_ws;
  unsigned short* xbf   = p; p += (size_t)4096 * 2048;
  unsigned short* WTqkv = p; p += (size_t)3072 * 2048;
  unsigned short* WoT   = p; p += (size_t)2048 * 2048;
  unsigned short* qkv   = p; p += (size_t)4096 * 3072;
  unsigned short* qTb   = p; p += (size_t)2 * 16 * 2048 * 128;
  unsigned short* kTb   = p; p += (size_t)2 * 4 * 2048 * 128;
  unsigned short* vTb   = p; p += (size_t)2 * 4 * 2048 * 128;
  unsigned short* ao    = p; p += (size_t)4096 * 2048;
  float2* rope_tab = (float2*)p; p += (size_t)2048 * 64 * 4;  // 1MB table

  // fused preprocessing: x-convert || weight transposes || RoPE table (512 blk)
  prep1<<<7168, 256, 0, stream>>>(x, Wq, Wk, Wv, Wo, xbf, WTqkv, WoT, rope_tab);

  // qkv projection: 8-phase 256x192, uniform 12-MFMA phases, 256 blocks = 1/CU
  gemm_nt_256x192<<<256, 512, 0, stream>>>(xbf, WTqkv, qkv, 4096, 3072, 2048);

  // fused: norm+rope (table-driven) || v-transpose
  prep2<<<2560, 256, 0, stream>>>(qkv, qw, kw, rope_tab, qTb, kTb, vTb);

  // flash: R8 geometry (128 q-rows, 4 waves, 2 blocks/CU), interleaved pack/PV
  flash_attn<<<512, 256, 0, stream>>>(qTb, kTb, vTb, ao);

  // output projection: 8-phase 128x256 -> 32 x 8 = 256 blocks = 1 per CU
  gemm_nt_128x256<<<256, 512, 0, stream>>>(ao, WoT, out, 4096, 2048, 2048);
}